// Round 1
// baseline (3985.648 us; speedup 1.0000x reference)
//
#include <hip/hip_runtime.h>
#include <math.h>

#define NGNN   32768
#define NMAXD  1024
#define HIDD   128
#define CLSD   64
#define DDIM   192
#define ATTH   128
#define NEDGE  200000
#define NEOUT  500000
#define NSUB   1024
#define KMIX   20
#define TE     32
#define GN     8

__device__ __forceinline__ float sigm(float x) { return 1.0f / (1.0f + __expf(-x)); }
__device__ __forceinline__ float tanhf_(float x) { return 2.0f / (1.0f + __expf(-2.0f * x)) - 1.0f; }

// ---------------- nf = A @ W_dec + b_dec, exploiting A in {0,1} with ~5% density
__global__ __launch_bounds__(128) void k_dec(
    const float* __restrict__ A, const float* __restrict__ Wd,
    const float* __restrict__ bd, float* __restrict__ nf) {
  __shared__ float arow[NMAXD];
  __shared__ int   nz[NMAXD];
  __shared__ int   cnt;
  const int row = blockIdx.x;
  const int t = threadIdx.x;
  if (t == 0) cnt = 0;
  const float4* A4 = (const float4*)(A + (size_t)row * NMAXD);
  float4* a4 = (float4*)arow;
  a4[t] = A4[t];
  a4[t + 128] = A4[t + 128];
  __syncthreads();
  for (int i = t; i < NMAXD; i += 128) {
    if (arow[i] != 0.0f) {
      int p = atomicAdd(&cnt, 1);
      nz[p] = i;
    }
  }
  __syncthreads();
  float acc = bd[t];
  const int n = cnt;
  for (int i = 0; i < n; i++) {
    acc += Wd[(size_t)nz[i] * HIDD + t];
  }
  nf[(size_t)row * HIDD + t] = acc;
}

// ---------------- state[i] = concat(nf[node_idx_feat[i]] (0-row aware), class_emb[class_label[i]])
__global__ __launch_bounds__(192) void k_state(
    const float* __restrict__ nf, const float* __restrict__ cemb,
    const int* __restrict__ nif, const int* __restrict__ cl,
    float* __restrict__ state) {
  const int i = blockIdx.x;
  const int t = threadIdx.x;
  float v;
  if (t < HIDD) {
    const int idx = nif[i];
    v = (idx == 0) ? 0.0f : nf[(size_t)(idx - 1) * HIDD + t];
  } else {
    v = cemb[cl[i] * CLSD + (t - HIDD)];
  }
  state[(size_t)i * DDIM + t] = v;
}

// ---------------- per-edge: diff -> (msg-hidden, att-hidden) -> msg*sigmoid(att) -> atomic agg[dst]
__global__ __launch_bounds__(256) void k_edge(
    const float* __restrict__ state, const int* __restrict__ edges,
    const int* __restrict__ attidx,
    const float* __restrict__ Wm1, const float* __restrict__ bm1,
    const float* __restrict__ Wm2, const float* __restrict__ bm2,
    const float* __restrict__ Wa1, const float* __restrict__ ba1,
    const float* __restrict__ Wa2, const float* __restrict__ ba2,
    float* __restrict__ agg) {
  __shared__ float bufA[TE][DDIM];  // diff, later hm (relu of msg layer1)
  __shared__ float bufB[TE][ATTH];  // ha (relu of att layer1)
  __shared__ int ssrc[TE], sdst[TE], sa0[TE], sa1[TE];
  const int t = threadIdx.x;
  const int e0 = blockIdx.x * TE;
  if (t < TE) {
    const int s = edges[2 * (e0 + t)];
    const int d = edges[2 * (e0 + t) + 1];
    ssrc[t] = s; sdst[t] = d;
    sa0[t] = attidx[s]; sa1[t] = attidx[d];
  }
  __syncthreads();
  if (t < DDIM) {
    for (int e = 0; e < TE; e++) {
      bufA[e][t] = state[(size_t)ssrc[e] * DDIM + t] - state[(size_t)sdst[e] * DDIM + t];
    }
  }
  __syncthreads();
  const int j0 = t & 63;
  const int eb = (t >> 6) * 8;

  // fused layer-1 for msg (192 cols) and att (128 cols); one-hot handled via row gathers
  float hmr[8][3], har[8][2];
#pragma unroll
  for (int i = 0; i < 8; i++) {
    const int a0 = sa0[eb + i], a1 = sa1[eb + i];
#pragma unroll
    for (int m = 0; m < 3; m++) {
      const int j = j0 + 64 * m;
      hmr[i][m] = bm1[j] + Wm1[(size_t)(DDIM + a0) * DDIM + j] + Wm1[(size_t)(DDIM + 64 + a1) * DDIM + j];
    }
#pragma unroll
    for (int m = 0; m < 2; m++) {
      const int j = j0 + 64 * m;
      har[i][m] = ba1[j] + Wa1[(size_t)(DDIM + a0) * ATTH + j] + Wa1[(size_t)(DDIM + 64 + a1) * ATTH + j];
    }
  }
  for (int k = 0; k < DDIM; k += 4) {
    float wm[4][3], wa[4][2];
#pragma unroll
    for (int kk = 0; kk < 4; kk++) {
#pragma unroll
      for (int m = 0; m < 3; m++) wm[kk][m] = Wm1[(size_t)(k + kk) * DDIM + j0 + 64 * m];
#pragma unroll
      for (int m = 0; m < 2; m++) wa[kk][m] = Wa1[(size_t)(k + kk) * ATTH + j0 + 64 * m];
    }
#pragma unroll
    for (int i = 0; i < 8; i++) {
      const float4 d4 = *(const float4*)&bufA[eb + i][k];
      const float dv[4] = {d4.x, d4.y, d4.z, d4.w};
#pragma unroll
      for (int kk = 0; kk < 4; kk++) {
#pragma unroll
        for (int m = 0; m < 3; m++) hmr[i][m] += dv[kk] * wm[kk][m];
#pragma unroll
        for (int m = 0; m < 2; m++) har[i][m] += dv[kk] * wa[kk][m];
      }
    }
  }
  __syncthreads();  // all diff reads done; overlay hm into bufA
#pragma unroll
  for (int i = 0; i < 8; i++) {
#pragma unroll
    for (int m = 0; m < 3; m++) bufA[eb + i][j0 + 64 * m] = fmaxf(hmr[i][m], 0.0f);
#pragma unroll
    for (int m = 0; m < 2; m++) bufB[eb + i][j0 + 64 * m] = fmaxf(har[i][m], 0.0f);
  }
  __syncthreads();

  // layer-2 for msg (K=192 over hm) and att (K=128 over ha), combine, scatter-add
  float macc[8][3], aacc[8][3];
#pragma unroll
  for (int i = 0; i < 8; i++) {
#pragma unroll
    for (int m = 0; m < 3; m++) {
      macc[i][m] = bm2[j0 + 64 * m];
      aacc[i][m] = ba2[j0 + 64 * m];
    }
  }
  for (int k = 0; k < DDIM; k += 4) {
    float w[4][3];
#pragma unroll
    for (int kk = 0; kk < 4; kk++)
#pragma unroll
      for (int m = 0; m < 3; m++) w[kk][m] = Wm2[(size_t)(k + kk) * DDIM + j0 + 64 * m];
#pragma unroll
    for (int i = 0; i < 8; i++) {
      const float4 d4 = *(const float4*)&bufA[eb + i][k];
      const float dv[4] = {d4.x, d4.y, d4.z, d4.w};
#pragma unroll
      for (int kk = 0; kk < 4; kk++)
#pragma unroll
        for (int m = 0; m < 3; m++) macc[i][m] += dv[kk] * w[kk][m];
    }
  }
  for (int k = 0; k < ATTH; k += 4) {
    float w[4][3];
#pragma unroll
    for (int kk = 0; kk < 4; kk++)
#pragma unroll
      for (int m = 0; m < 3; m++) w[kk][m] = Wa2[(size_t)(k + kk) * DDIM + j0 + 64 * m];
#pragma unroll
    for (int i = 0; i < 8; i++) {
      const float4 d4 = *(const float4*)&bufB[eb + i][k];
      const float dv[4] = {d4.x, d4.y, d4.z, d4.w};
#pragma unroll
      for (int kk = 0; kk < 4; kk++)
#pragma unroll
        for (int m = 0; m < 3; m++) aacc[i][m] += dv[kk] * w[kk][m];
    }
  }
#pragma unroll
  for (int i = 0; i < 8; i++) {
    const int d = sdst[eb + i];
#pragma unroll
    for (int m = 0; m < 3; m++) {
      atomicAdd(&agg[(size_t)d * DDIM + j0 + 64 * m], macc[i][m] * sigm(aacc[i][m]));
    }
  }
}

// ---------------- GRU: gi = agg@W_ih+b, gh = state@W_hh+b, gated update (in place)
__global__ __launch_bounds__(192) void k_gru(
    float* __restrict__ state, const float* __restrict__ agg,
    const float* __restrict__ Wih, const float* __restrict__ bih,
    const float* __restrict__ Whh, const float* __restrict__ bhh) {
  __shared__ float sagg[GN][DDIM];
  __shared__ float sst[GN][DDIM];
  const int t = threadIdx.x;
  const int n0 = blockIdx.x * GN;
#pragma unroll
  for (int n = 0; n < GN; n++) {
    sagg[n][t] = agg[(size_t)(n0 + n) * DDIM + t];
    sst[n][t] = state[(size_t)(n0 + n) * DDIM + t];
  }
  __syncthreads();
  const int d = t;
  float ir[GN], iz[GN], in_[GN], hr[GN], hz[GN], hn[GN];
#pragma unroll
  for (int n = 0; n < GN; n++) {
    ir[n] = bih[d]; iz[n] = bih[DDIM + d]; in_[n] = bih[2 * DDIM + d];
    hr[n] = bhh[d]; hz[n] = bhh[DDIM + d]; hn[n] = bhh[2 * DDIM + d];
  }
  for (int k = 0; k < DDIM; k += 4) {
    float wi[4][3], wh[4][3];
#pragma unroll
    for (int kk = 0; kk < 4; kk++) {
      const size_t ro = (size_t)(k + kk) * 576;
      wi[kk][0] = Wih[ro + d];
      wi[kk][1] = Wih[ro + DDIM + d];
      wi[kk][2] = Wih[ro + 2 * DDIM + d];
      wh[kk][0] = Whh[ro + d];
      wh[kk][1] = Whh[ro + DDIM + d];
      wh[kk][2] = Whh[ro + 2 * DDIM + d];
    }
#pragma unroll
    for (int n = 0; n < GN; n++) {
      const float4 a4 = *(const float4*)&sagg[n][k];
      const float4 s4 = *(const float4*)&sst[n][k];
      const float av[4] = {a4.x, a4.y, a4.z, a4.w};
      const float sv[4] = {s4.x, s4.y, s4.z, s4.w};
#pragma unroll
      for (int kk = 0; kk < 4; kk++) {
        ir[n] += av[kk] * wi[kk][0];
        iz[n] += av[kk] * wi[kk][1];
        in_[n] += av[kk] * wi[kk][2];
        hr[n] += sv[kk] * wh[kk][0];
        hz[n] += sv[kk] * wh[kk][1];
        hn[n] += sv[kk] * wh[kk][2];
      }
    }
  }
#pragma unroll
  for (int n = 0; n < GN; n++) {
    const float r = sigm(ir[n] + hr[n]);
    const float z = sigm(iz[n] + hz[n]);
    const float nn = tanhf_(in_[n] + r * hn[n]);
    state[(size_t)(n0 + n) * DDIM + d] = (1.0f - z) * nn + z * sst[n][d];
  }
}

// ---------------- head MLP layers (32 rows per block, 256 threads)
template <int K>
__device__ __forceinline__ void layer128_relu(
    const float* __restrict__ in, const float* __restrict__ W,
    const float* __restrict__ b, float* __restrict__ out, int t) {
  const int j0 = t & 63;
  const int eb = (t >> 6) * 8;
  float acc[8][2];
#pragma unroll
  for (int i = 0; i < 8; i++) { acc[i][0] = b[j0]; acc[i][1] = b[j0 + 64]; }
  for (int k = 0; k < K; k += 4) {
    float w[4][2];
#pragma unroll
    for (int kk = 0; kk < 4; kk++) {
      w[kk][0] = W[(size_t)(k + kk) * HIDD + j0];
      w[kk][1] = W[(size_t)(k + kk) * HIDD + j0 + 64];
    }
#pragma unroll
    for (int i = 0; i < 8; i++) {
      const float4 d4 = *(const float4*)&in[(eb + i) * K + k];
      const float dv[4] = {d4.x, d4.y, d4.z, d4.w};
#pragma unroll
      for (int kk = 0; kk < 4; kk++) {
        acc[i][0] += dv[kk] * w[kk][0];
        acc[i][1] += dv[kk] * w[kk][1];
      }
    }
  }
#pragma unroll
  for (int i = 0; i < 8; i++) {
    out[(eb + i) * HIDD + j0] = fmaxf(acc[i][0], 0.0f);
    out[(eb + i) * HIDD + j0 + 64] = fmaxf(acc[i][1], 0.0f);
  }
}

__device__ __forceinline__ void layer20(
    const float* __restrict__ in, const float* __restrict__ W,
    const float* __restrict__ b, int t, float acc[4]) {
  const int c = t & 31;
  const int rbase = (t >> 5) * 4;
  if (c >= KMIX) return;
#pragma unroll
  for (int i = 0; i < 4; i++) acc[i] = b[c];
  for (int k = 0; k < HIDD; k += 4) {
    float w[4];
#pragma unroll
    for (int kk = 0; kk < 4; kk++) w[kk] = W[(size_t)(k + kk) * KMIX + c];
#pragma unroll
    for (int i = 0; i < 4; i++) {
      const float4 d4 = *(const float4*)&in[(rbase + i) * HIDD + k];
      const float dv[4] = {d4.x, d4.y, d4.z, d4.w};
#pragma unroll
      for (int kk = 0; kk < 4; kk++) acc[i] += dv[kk] * w[kk];
    }
  }
}

__global__ __launch_bounds__(256) void k_head(
    const float* __restrict__ state, const int* __restrict__ nig,
    const float* __restrict__ label, const int* __restrict__ subidx,
    const float* __restrict__ Wt1, const float* __restrict__ bt1,
    const float* __restrict__ Wt2, const float* __restrict__ bt2,
    const float* __restrict__ Wt3, const float* __restrict__ bt3,
    const float* __restrict__ Wa1, const float* __restrict__ ba1,
    const float* __restrict__ Wa2, const float* __restrict__ ba2,
    const float* __restrict__ Wa3, const float* __restrict__ ba3,
    float* __restrict__ red_loss, float* __restrict__ red_alpha,
    float* __restrict__ cnt) {
  __shared__ float dout[32][DDIM];
  __shared__ float h1[32][HIDD];
  __shared__ float h2[32][HIDD];
  __shared__ float la[32][KMIX];
  __shared__ float lse[32];
  __shared__ int ssub[32];
  __shared__ float slab[32];
  const int t = threadIdx.x;
  const int r0 = blockIdx.x * 32;
  if (t < 32) {
    ssub[t] = subidx[r0 + t];
    slab[t] = label[r0 + t];
  }
  if (t < DDIM) {
    for (int r = 0; r < 32; r++) {
      const int ia = nig[2 * (r0 + r)];
      const int ib = nig[2 * (r0 + r) + 1];
      dout[r][t] = state[(size_t)ia * DDIM + t] - state[(size_t)ib * DDIM + t];
    }
  }
  __syncthreads();
  const int c = t & 31;
  const int rbase = (t >> 5) * 4;

  // ---- theta branch ----
  layer128_relu<DDIM>(&dout[0][0], Wt1, bt1, &h1[0][0], t);
  __syncthreads();
  layer128_relu<HIDD>(&h1[0][0], Wt2, bt2, &h2[0][0], t);
  __syncthreads();
  {
    float acc[4];
    layer20(&h2[0][0], Wt3, bt3, t, acc);
    if (c < KMIX) {
#pragma unroll
      for (int i = 0; i < 4; i++) {
        const int r = rbase + i;
        const float lt = acc[i];
        const float adj = fmaxf(lt, 0.0f) + logf(1.0f + __expf(-fabsf(lt))) - lt * slab[r];
        atomicAdd(&red_loss[ssub[r] * KMIX + c], adj);
      }
    }
    if (c == 0) {
#pragma unroll
      for (int i = 0; i < 4; i++) atomicAdd(&cnt[ssub[rbase + i]], 1.0f);
    }
  }
  __syncthreads();
  // ---- alpha branch ----
  layer128_relu<DDIM>(&dout[0][0], Wa1, ba1, &h1[0][0], t);
  __syncthreads();
  layer128_relu<HIDD>(&h1[0][0], Wa2, ba2, &h2[0][0], t);
  __syncthreads();
  {
    float acc[4];
    layer20(&h2[0][0], Wa3, ba3, t, acc);
    if (c < KMIX) {
#pragma unroll
      for (int i = 0; i < 4; i++) la[rbase + i][c] = acc[i];
    }
  }
  __syncthreads();
  if (t < 32) {
    float m = -1e30f;
    for (int k = 0; k < KMIX; k++) m = fmaxf(m, la[t][k]);
    float s = 0.0f;
    for (int k = 0; k < KMIX; k++) s += __expf(la[t][k] - m);
    lse[t] = m + logf(s);
  }
  __syncthreads();
  if (c < KMIX) {
#pragma unroll
    for (int i = 0; i < 4; i++) {
      const int r = rbase + i;
      atomicAdd(&red_alpha[ssub[r] * KMIX + c], la[r][c] - lse[r]);
    }
  }
}

// ---------------- final: per-subgraph logsumexp, reduce to scalar
__global__ __launch_bounds__(1024) void k_final(
    const float* __restrict__ red_loss, const float* __restrict__ red_alpha,
    const float* __restrict__ cnt, float* __restrict__ out) {
  __shared__ float part[1024];
  const int s = threadIdx.x;
  const float c = fmaxf(cnt[s], 1.0f);
  float v[KMIX];
  float m = -1e30f;
  for (int k = 0; k < KMIX; k++) {
    v[k] = -red_loss[s * KMIX + k] + red_alpha[s * KMIX + k] / c;
    m = fmaxf(m, v[k]);
  }
  float sum = 0.0f;
  for (int k = 0; k < KMIX; k++) sum += __expf(v[k] - m);
  part[s] = m + logf(sum);
  __syncthreads();
  for (int st = 512; st > 0; st >>= 1) {
    if (s < st) part[s] += part[s + st];
    __syncthreads();
  }
  if (s == 0) out[0] = -part[0] / (float)NEOUT;
}

extern "C" void kernel_launch(void* const* d_in, const int* in_sizes, int n_in,
                              void* d_out, int out_size, void* d_ws, size_t ws_size,
                              hipStream_t stream) {
  const float* A      = (const float*)d_in[0];
  const int*   edges  = (const int*)d_in[1];
  const int*   attidx = (const int*)d_in[2];
  const int*   nif    = (const int*)d_in[3];
  const int*   cl     = (const int*)d_in[4];
  const int*   nig    = (const int*)d_in[5];
  const float* label  = (const float*)d_in[6];
  const int*   subidx = (const int*)d_in[7];
  const float* Wdec   = (const float*)d_in[8];
  const float* bdec   = (const float*)d_in[9];
  const float* cemb   = (const float*)d_in[10];
  const float* Wm1    = (const float*)d_in[11];
  const float* bm1    = (const float*)d_in[12];
  const float* Wm2    = (const float*)d_in[13];
  const float* bm2    = (const float*)d_in[14];
  const float* Wa1    = (const float*)d_in[15];
  const float* ba1    = (const float*)d_in[16];
  const float* Wa2    = (const float*)d_in[17];
  const float* ba2    = (const float*)d_in[18];
  const float* Wih    = (const float*)d_in[19];
  const float* bih    = (const float*)d_in[20];
  const float* Whh    = (const float*)d_in[21];
  const float* bhh    = (const float*)d_in[22];
  const float* Wt1    = (const float*)d_in[23];
  const float* bt1    = (const float*)d_in[24];
  const float* Wt2    = (const float*)d_in[25];
  const float* bt2    = (const float*)d_in[26];
  const float* Wt3    = (const float*)d_in[27];
  const float* bt3    = (const float*)d_in[28];
  const float* Wha1   = (const float*)d_in[29];
  const float* hba1   = (const float*)d_in[30];
  const float* Wha2   = (const float*)d_in[31];
  const float* hba2   = (const float*)d_in[32];
  const float* Wha3   = (const float*)d_in[33];
  const float* hba3   = (const float*)d_in[34];

  char* ws = (char*)d_ws;
  const size_t SZ_STATE = (size_t)NGNN * DDIM * sizeof(float);   // 25.2 MB
  float* state     = (float*)ws;
  float* agg       = (float*)(ws + SZ_STATE);
  float* nf        = agg;  // decode output lives where agg will go (dead before first memset)
  float* red_loss  = (float*)(ws + 2 * SZ_STATE);
  float* red_alpha = red_loss + NSUB * KMIX;
  float* cnt       = red_alpha + NSUB * KMIX;

  k_dec<<<NGNN, 128, 0, stream>>>(A, Wdec, bdec, nf);
  k_state<<<NGNN, 192, 0, stream>>>(nf, cemb, nif, cl, state);
  for (int p = 0; p < 2; p++) {
    hipMemsetAsync(agg, 0, SZ_STATE, stream);
    k_edge<<<NEDGE / TE, 256, 0, stream>>>(state, edges, attidx,
        Wm1, bm1, Wm2, bm2, Wa1, ba1, Wa2, ba2, agg);
    k_gru<<<NGNN / GN, 192, 0, stream>>>(state, agg, Wih, bih, Whh, bhh);
  }
  hipMemsetAsync(red_loss, 0, (size_t)(2 * NSUB * KMIX + NSUB) * sizeof(float), stream);
  k_head<<<NEOUT / 32, 256, 0, stream>>>(state, nig, label, subidx,
      Wt1, bt1, Wt2, bt2, Wt3, bt3, Wha1, hba1, Wha2, hba2, Wha3, hba3,
      red_loss, red_alpha, cnt);
  k_final<<<1, 1024, 0, stream>>>(red_loss, red_alpha, cnt, (float*)d_out);
}

// Round 2
// 1520.509 us; speedup vs baseline: 2.6213x; 2.6213x over previous
//
#include <hip/hip_runtime.h>
#include <math.h>

#define NGNN   32768
#define NMAXD  1024
#define HIDD   128
#define CLSD   64
#define DDIM   192
#define ATTH   128
#define NEDGE  200000
#define NEOUT  500000
#define NSUB   1024
#define KMIX   20
#define GN     8

typedef __attribute__((ext_vector_type(8))) short bf16x8;
typedef __attribute__((ext_vector_type(4))) float f32x4;

__device__ __forceinline__ float sigm(float x) { return 1.0f / (1.0f + __expf(-x)); }
__device__ __forceinline__ float tanhf_(float x) { return 2.0f / (1.0f + __expf(-2.0f * x)) - 1.0f; }

__device__ __forceinline__ short f2bf(float f) {
  union { float f; unsigned u; } v; v.f = f;
  unsigned r = v.u + 0x7FFFu + ((v.u >> 16) & 1u);
  return (short)(r >> 16);
}

// ---------------- pack fp32 [K][N] weight into bf16 MFMA B-fragment order:
// out[((ks*CT+ct)*64 + l)*8 + j] = W[(ks*32 + (l>>4)*8 + j)][ct*16 + (l&15)]  (0 if col>=N)
__global__ __launch_bounds__(64) void k_pack(const float* __restrict__ W,
                                             short* __restrict__ out, int N, int CT) {
  const int l = threadIdx.x;
  const int ks = blockIdx.x / CT;
  const int ct = blockIdx.x % CT;
  const int row0 = ks * 32 + (l >> 4) * 8;
  const int col = ct * 16 + (l & 15);
  short v[8];
#pragma unroll
  for (int j = 0; j < 8; j++) {
    const float f = (col < N) ? W[(size_t)(row0 + j) * N + col] : 0.0f;
    v[j] = f2bf(f);
  }
  *(bf16x8*)(out + ((size_t)blockIdx.x * 64 + l) * 8) = *(bf16x8*)v;
}

// ---------------- nf = A @ W_dec + b_dec, exploiting A in {0,1} with ~5% density
__global__ __launch_bounds__(128) void k_dec(
    const float* __restrict__ A, const float* __restrict__ Wd,
    const float* __restrict__ bd, float* __restrict__ nf) {
  __shared__ float arow[NMAXD];
  __shared__ int   nz[NMAXD];
  __shared__ int   cnt;
  const int row = blockIdx.x;
  const int t = threadIdx.x;
  if (t == 0) cnt = 0;
  const float4* A4 = (const float4*)(A + (size_t)row * NMAXD);
  float4* a4 = (float4*)arow;
  a4[t] = A4[t];
  a4[t + 128] = A4[t + 128];
  __syncthreads();
  for (int i = t; i < NMAXD; i += 128) {
    if (arow[i] != 0.0f) {
      int p = atomicAdd(&cnt, 1);
      nz[p] = i;
    }
  }
  __syncthreads();
  float acc = bd[t];
  const int n = cnt;
  for (int i = 0; i < n; i++) acc += Wd[(size_t)nz[i] * HIDD + t];
  nf[(size_t)row * HIDD + t] = acc;
}

// ---------------- state[i] = concat(nf[nif[i]] (0-row aware), class_emb[cl[i]])
__global__ __launch_bounds__(192) void k_state(
    const float* __restrict__ nf, const float* __restrict__ cemb,
    const int* __restrict__ nif, const int* __restrict__ cl,
    float* __restrict__ state) {
  const int i = blockIdx.x;
  const int t = threadIdx.x;
  float v;
  if (t < HIDD) {
    const int idx = nif[i];
    v = (idx == 0) ? 0.0f : nf[(size_t)(idx - 1) * HIDD + t];
  } else {
    v = cemb[cl[i] * CLSD + (t - HIDD)];
  }
  state[(size_t)i * DDIM + t] = v;
}

// ---------------- MFMA edge kernel: 32 edges/block, 128 threads (2 waves)
__global__ __launch_bounds__(128, 2) void k_edge_mfma(
    const float* __restrict__ state, const int* __restrict__ edges,
    const int* __restrict__ attidx,
    const float* __restrict__ Wm1, const float* __restrict__ bm1,
    const short* __restrict__ pWm1, const short* __restrict__ pWm2,
    const float* __restrict__ bm2,
    const float* __restrict__ Wa1, const float* __restrict__ ba1,
    const short* __restrict__ pWa1, const short* __restrict__ pWa2,
    const float* __restrict__ ba2,
    float* __restrict__ agg) {
  __shared__ short pdiff[6144];  // [rt<2][ks<6][lane<64][8]  K=192 A-frags
  __shared__ short phm[6144];    // hm A-frags (K=192)
  __shared__ short pha[4096];    // ha A-frags (K=128)
  const int t = threadIdx.x;
  const int e0 = blockIdx.x * 32;

  // stage diff -> pdiff in A-fragment order
  for (int it = 0; it < 6; it++) {
    const int id = t + 128 * it;      // 768 tasks: 32 rows x 24 col-groups
    const int r = id / 24, g24 = id % 24;
    const int e = e0 + r;
    const int s = edges[2 * e], d = edges[2 * e + 1];
    const float4 a0 = *(const float4*)&state[(size_t)s * DDIM + g24 * 8];
    const float4 a1 = *(const float4*)&state[(size_t)s * DDIM + g24 * 8 + 4];
    const float4 b0 = *(const float4*)&state[(size_t)d * DDIM + g24 * 8];
    const float4 b1 = *(const float4*)&state[(size_t)d * DDIM + g24 * 8 + 4];
    short s8[8];
    s8[0] = f2bf(a0.x - b0.x); s8[1] = f2bf(a0.y - b0.y);
    s8[2] = f2bf(a0.z - b0.z); s8[3] = f2bf(a0.w - b0.w);
    s8[4] = f2bf(a1.x - b1.x); s8[5] = f2bf(a1.y - b1.y);
    s8[6] = f2bf(a1.z - b1.z); s8[7] = f2bf(a1.w - b1.w);
    const int rt = r >> 4, ks = g24 >> 2, g = g24 & 3;
    *(bf16x8*)&pdiff[((rt * 6 + ks) * 64 + g * 16 + (r & 15)) * 8] = *(bf16x8*)s8;
  }

  const int wid = t >> 6, l = t & 63;
  const int col16 = l & 15, rr = (l >> 4) * 4;
  // per-lane metadata for its 4 output rows
  int a0r[4], a1r[4], dstr[4];
#pragma unroll
  for (int j = 0; j < 4; j++) {
    const int e = e0 + wid * 16 + rr + j;
    const int s = edges[2 * e], d = edges[2 * e + 1];
    a0r[j] = attidx[s]; a1r[j] = attidx[d]; dstr[j] = d;
  }
  __syncthreads();

  // msg L1: [32x192]@[192x192], one-hot part via fp32 gathers into acc init
  for (int ct = 0; ct < 12; ct++) {
    const int col = ct * 16 + col16;
    f32x4 acc;
#pragma unroll
    for (int j = 0; j < 4; j++)
      acc[j] = bm1[col] + Wm1[(size_t)(DDIM + a0r[j]) * DDIM + col]
                        + Wm1[(size_t)(DDIM + 64 + a1r[j]) * DDIM + col];
    for (int ks = 0; ks < 6; ks++) {
      bf16x8 a = *(const bf16x8*)&pdiff[((wid * 6 + ks) * 64 + l) * 8];
      bf16x8 b = *(const bf16x8*)&pWm1[((ks * 12 + ct) * 64 + l) * 8];
      acc = __builtin_amdgcn_mfma_f32_16x16x32_bf16(a, b, acc, 0, 0, 0);
    }
    const int ksp = col >> 5, gp = (col & 31) >> 3, jp = col & 7;
#pragma unroll
    for (int j = 0; j < 4; j++)
      phm[((wid * 6 + ksp) * 64 + gp * 16 + rr + j) * 8 + jp] = f2bf(fmaxf(acc[j], 0.0f));
  }
  // att L1: [32x192]@[192x128]
  for (int ct = 0; ct < 8; ct++) {
    const int col = ct * 16 + col16;
    f32x4 acc;
#pragma unroll
    for (int j = 0; j < 4; j++)
      acc[j] = ba1[col] + Wa1[(size_t)(DDIM + a0r[j]) * ATTH + col]
                        + Wa1[(size_t)(DDIM + 64 + a1r[j]) * ATTH + col];
    for (int ks = 0; ks < 6; ks++) {
      bf16x8 a = *(const bf16x8*)&pdiff[((wid * 6 + ks) * 64 + l) * 8];
      bf16x8 b = *(const bf16x8*)&pWa1[((ks * 8 + ct) * 64 + l) * 8];
      acc = __builtin_amdgcn_mfma_f32_16x16x32_bf16(a, b, acc, 0, 0, 0);
    }
    const int ksp = ct >> 1, gp = ((ct & 1) * 16 + col16) >> 3, jp = col16 & 7;
#pragma unroll
    for (int j = 0; j < 4; j++)
      pha[((wid * 4 + ksp) * 64 + gp * 16 + rr + j) * 8 + jp] = f2bf(fmaxf(acc[j], 0.0f));
  }
  __syncthreads();

  // L2 (msg: K=192, att: K=128, both N=192), combine msg*sigm(att), scatter-add
  for (int ct = 0; ct < 12; ct++) {
    const int col = ct * 16 + col16;
    f32x4 m, av;
    const float bm = bm2[col], ba = ba2[col];
    m[0] = bm; m[1] = bm; m[2] = bm; m[3] = bm;
    av[0] = ba; av[1] = ba; av[2] = ba; av[3] = ba;
    for (int ks = 0; ks < 6; ks++) {
      bf16x8 a = *(const bf16x8*)&phm[((wid * 6 + ks) * 64 + l) * 8];
      bf16x8 b = *(const bf16x8*)&pWm2[((ks * 12 + ct) * 64 + l) * 8];
      m = __builtin_amdgcn_mfma_f32_16x16x32_bf16(a, b, m, 0, 0, 0);
    }
    for (int ks = 0; ks < 4; ks++) {
      bf16x8 a = *(const bf16x8*)&pha[((wid * 4 + ks) * 64 + l) * 8];
      bf16x8 b = *(const bf16x8*)&pWa2[((ks * 12 + ct) * 64 + l) * 8];
      av = __builtin_amdgcn_mfma_f32_16x16x32_bf16(a, b, av, 0, 0, 0);
    }
#pragma unroll
    for (int j = 0; j < 4; j++) {
      atomicAdd(&agg[(size_t)dstr[j] * DDIM + col], m[j] * sigm(av[j]));
    }
  }
}

// ---------------- GRU (fp32): gi = agg@W_ih+b, gh = state@W_hh+b, gated update
__global__ __launch_bounds__(192) void k_gru(
    float* __restrict__ state, const float* __restrict__ agg,
    const float* __restrict__ Wih, const float* __restrict__ bih,
    const float* __restrict__ Whh, const float* __restrict__ bhh) {
  __shared__ float sagg[GN][DDIM];
  __shared__ float sst[GN][DDIM];
  const int t = threadIdx.x;
  const int n0 = blockIdx.x * GN;
#pragma unroll
  for (int n = 0; n < GN; n++) {
    sagg[n][t] = agg[(size_t)(n0 + n) * DDIM + t];
    sst[n][t] = state[(size_t)(n0 + n) * DDIM + t];
  }
  __syncthreads();
  const int d = t;
  float ir[GN], iz[GN], in_[GN], hr[GN], hz[GN], hn[GN];
#pragma unroll
  for (int n = 0; n < GN; n++) {
    ir[n] = bih[d]; iz[n] = bih[DDIM + d]; in_[n] = bih[2 * DDIM + d];
    hr[n] = bhh[d]; hz[n] = bhh[DDIM + d]; hn[n] = bhh[2 * DDIM + d];
  }
  for (int k = 0; k < DDIM; k += 4) {
    float wi[4][3], wh[4][3];
#pragma unroll
    for (int kk = 0; kk < 4; kk++) {
      const size_t ro = (size_t)(k + kk) * 576;
      wi[kk][0] = Wih[ro + d];
      wi[kk][1] = Wih[ro + DDIM + d];
      wi[kk][2] = Wih[ro + 2 * DDIM + d];
      wh[kk][0] = Whh[ro + d];
      wh[kk][1] = Whh[ro + DDIM + d];
      wh[kk][2] = Whh[ro + 2 * DDIM + d];
    }
#pragma unroll
    for (int n = 0; n < GN; n++) {
      const float4 a4 = *(const float4*)&sagg[n][k];
      const float4 s4 = *(const float4*)&sst[n][k];
      const float av[4] = {a4.x, a4.y, a4.z, a4.w};
      const float sv[4] = {s4.x, s4.y, s4.z, s4.w};
#pragma unroll
      for (int kk = 0; kk < 4; kk++) {
        ir[n] += av[kk] * wi[kk][0];
        iz[n] += av[kk] * wi[kk][1];
        in_[n] += av[kk] * wi[kk][2];
        hr[n] += sv[kk] * wh[kk][0];
        hz[n] += sv[kk] * wh[kk][1];
        hn[n] += sv[kk] * wh[kk][2];
      }
    }
  }
#pragma unroll
  for (int n = 0; n < GN; n++) {
    const float r = sigm(ir[n] + hr[n]);
    const float z = sigm(iz[n] + hz[n]);
    const float nn = tanhf_(in_[n] + r * hn[n]);
    state[(size_t)(n0 + n) * DDIM + d] = (1.0f - z) * nn + z * sst[n][d];
  }
}

// ---------------- MFMA head: 64 rows/block, 256 threads (4 waves)
__device__ __forceinline__ void head_branch(
    const short* pd, short* ph1, short* ph2,
    const short* __restrict__ pW1, const float* __restrict__ b1,
    const short* __restrict__ pW2, const float* __restrict__ b2,
    const short* __restrict__ pW3, const float* __restrict__ b3,
    int wid, int l, f32x4 out3[2]) {
  const int col16 = l & 15, rr = (l >> 4) * 4;
  // L1: K=192, N=128
  for (int ct = 0; ct < 8; ct++) {
    const int col = ct * 16 + col16;
    f32x4 acc;
    const float bb = b1[col];
    acc[0] = bb; acc[1] = bb; acc[2] = bb; acc[3] = bb;
    for (int ks = 0; ks < 6; ks++) {
      bf16x8 a = *(const bf16x8*)&pd[((wid * 6 + ks) * 64 + l) * 8];
      bf16x8 b = *(const bf16x8*)&pW1[((ks * 8 + ct) * 64 + l) * 8];
      acc = __builtin_amdgcn_mfma_f32_16x16x32_bf16(a, b, acc, 0, 0, 0);
    }
    const int ksp = ct >> 1, gp = ((ct & 1) * 16 + col16) >> 3, jp = col16 & 7;
#pragma unroll
    for (int j = 0; j < 4; j++)
      ph1[((wid * 4 + ksp) * 64 + gp * 16 + rr + j) * 8 + jp] = f2bf(fmaxf(acc[j], 0.0f));
  }
  __syncthreads();
  // L2: K=128, N=128
  for (int ct = 0; ct < 8; ct++) {
    const int col = ct * 16 + col16;
    f32x4 acc;
    const float bb = b2[col];
    acc[0] = bb; acc[1] = bb; acc[2] = bb; acc[3] = bb;
    for (int ks = 0; ks < 4; ks++) {
      bf16x8 a = *(const bf16x8*)&ph1[((wid * 4 + ks) * 64 + l) * 8];
      bf16x8 b = *(const bf16x8*)&pW2[((ks * 8 + ct) * 64 + l) * 8];
      acc = __builtin_amdgcn_mfma_f32_16x16x32_bf16(a, b, acc, 0, 0, 0);
    }
    const int ksp = ct >> 1, gp = ((ct & 1) * 16 + col16) >> 3, jp = col16 & 7;
#pragma unroll
    for (int j = 0; j < 4; j++)
      ph2[((wid * 4 + ksp) * 64 + gp * 16 + rr + j) * 8 + jp] = f2bf(fmaxf(acc[j], 0.0f));
  }
  __syncthreads();
  // L3: K=128, N=32 (cols >= 20 are zero-padded in pW3)
  for (int ct = 0; ct < 2; ct++) {
    const int col = ct * 16 + col16;
    f32x4 acc;
    const float bb = (col < KMIX) ? b3[col] : 0.0f;
    acc[0] = bb; acc[1] = bb; acc[2] = bb; acc[3] = bb;
    for (int ks = 0; ks < 4; ks++) {
      bf16x8 a = *(const bf16x8*)&ph2[((wid * 4 + ks) * 64 + l) * 8];
      bf16x8 b = *(const bf16x8*)&pW3[((ks * 2 + ct) * 64 + l) * 8];
      acc = __builtin_amdgcn_mfma_f32_16x16x32_bf16(a, b, acc, 0, 0, 0);
    }
    out3[ct] = acc;
  }
}

__global__ __launch_bounds__(256, 2) void k_head_mfma(
    const float* __restrict__ state, const int* __restrict__ nig,
    const float* __restrict__ label, const int* __restrict__ subidx,
    const short* __restrict__ pWt1, const float* __restrict__ bt1,
    const short* __restrict__ pWt2, const float* __restrict__ bt2,
    const short* __restrict__ pWt3, const float* __restrict__ bt3,
    const short* __restrict__ pWa1, const float* __restrict__ ba1,
    const short* __restrict__ pWa2, const float* __restrict__ ba2,
    const short* __restrict__ pWa3, const float* __restrict__ ba3,
    float* __restrict__ red_loss, float* __restrict__ red_alpha,
    float* __restrict__ cnt) {
  __shared__ short pd[12288];   // dout A-frags [rt<4][ks<6][64][8]
  __shared__ short ph1[8192];   // [rt<4][ks<4][64][8]
  __shared__ short ph2[8192];
  __shared__ int   ssub[64];
  __shared__ float slab[64];
  __shared__ float lse[64];
  float* la = (float*)pd;       // [64][20] overlay; first write is after last pd read

  const int t = threadIdx.x;
  const int r0 = blockIdx.x * 64;

  if (t < 64) {
    const int gr = r0 + t;
    const int sb = (gr < NEOUT) ? subidx[gr] : 0;
    ssub[t] = sb;
    slab[t] = (gr < NEOUT) ? label[gr] : 0.0f;
    if (gr < NEOUT) atomicAdd(&cnt[sb], 1.0f);
  }
  for (int it = 0; it < 6; it++) {
    const int id = t + 256 * it;      // 1536 tasks: 64 rows x 24 col-groups
    const int r = id / 24, g24 = id % 24;
    const int gr = r0 + r;
    float v[8];
    if (gr < NEOUT) {
      const int ia = nig[2 * gr], ib = nig[2 * gr + 1];
      const float4 a0 = *(const float4*)&state[(size_t)ia * DDIM + g24 * 8];
      const float4 a1 = *(const float4*)&state[(size_t)ia * DDIM + g24 * 8 + 4];
      const float4 b0 = *(const float4*)&state[(size_t)ib * DDIM + g24 * 8];
      const float4 b1 = *(const float4*)&state[(size_t)ib * DDIM + g24 * 8 + 4];
      v[0] = a0.x - b0.x; v[1] = a0.y - b0.y; v[2] = a0.z - b0.z; v[3] = a0.w - b0.w;
      v[4] = a1.x - b1.x; v[5] = a1.y - b1.y; v[6] = a1.z - b1.z; v[7] = a1.w - b1.w;
    } else {
#pragma unroll
      for (int j = 0; j < 8; j++) v[j] = 0.0f;
    }
    short s8[8];
#pragma unroll
    for (int j = 0; j < 8; j++) s8[j] = f2bf(v[j]);
    const int rt = r >> 4, ks = g24 >> 2, g = g24 & 3;
    *(bf16x8*)&pd[((rt * 6 + ks) * 64 + g * 16 + (r & 15)) * 8] = *(bf16x8*)s8;
  }
  __syncthreads();

  const int wid = t >> 6, l = t & 63;
  const int col16 = l & 15, rr = (l >> 4) * 4;
  f32x4 out3[2];

  // ---- theta ----
  head_branch(pd, ph1, ph2, pWt1, bt1, pWt2, bt2, pWt3, bt3, wid, l, out3);
#pragma unroll
  for (int ct = 0; ct < 2; ct++) {
    const int col = ct * 16 + col16;
    if (col < KMIX) {
#pragma unroll
      for (int j = 0; j < 4; j++) {
        const int r = wid * 16 + rr + j;
        if (r0 + r < NEOUT) {
          const float lt = out3[ct][j];
          const float adj = fmaxf(lt, 0.0f) + logf(1.0f + __expf(-fabsf(lt))) - lt * slab[r];
          atomicAdd(&red_loss[ssub[r] * KMIX + col], adj);
        }
      }
    }
  }
  // ---- alpha ----
  head_branch(pd, ph1, ph2, pWa1, ba1, pWa2, ba2, pWa3, ba3, wid, l, out3);
#pragma unroll
  for (int ct = 0; ct < 2; ct++) {
    const int col = ct * 16 + col16;
    if (col < KMIX) {
#pragma unroll
      for (int j = 0; j < 4; j++) {
        const int r = wid * 16 + rr + j;
        la[r * KMIX + col] = out3[ct][j];
      }
    }
  }
  __syncthreads();
  if (t < 64) {
    float m = -1e30f;
    for (int k = 0; k < KMIX; k++) m = fmaxf(m, la[t * KMIX + k]);
    float s = 0.0f;
    for (int k = 0; k < KMIX; k++) s += __expf(la[t * KMIX + k] - m);
    lse[t] = m + logf(s);
  }
  __syncthreads();
  {
    const int r = t >> 2;
    if (r0 + r < NEOUT) {
      for (int i = 0; i < 5; i++) {
        const int c = (t & 3) + 4 * i;
        atomicAdd(&red_alpha[ssub[r] * KMIX + c], la[r * KMIX + c] - lse[r]);
      }
    }
  }
}

// ---------------- final: per-subgraph logsumexp, reduce to scalar
__global__ __launch_bounds__(1024) void k_final(
    const float* __restrict__ red_loss, const float* __restrict__ red_alpha,
    const float* __restrict__ cnt, float* __restrict__ out) {
  __shared__ float part[1024];
  const int s = threadIdx.x;
  const float c = fmaxf(cnt[s], 1.0f);
  float v[KMIX];
  float m = -1e30f;
  for (int k = 0; k < KMIX; k++) {
    v[k] = -red_loss[s * KMIX + k] + red_alpha[s * KMIX + k] / c;
    m = fmaxf(m, v[k]);
  }
  float sum = 0.0f;
  for (int k = 0; k < KMIX; k++) sum += __expf(v[k] - m);
  part[s] = m + logf(sum);
  __syncthreads();
  for (int st = 512; st > 0; st >>= 1) {
    if (s < st) part[s] += part[s + st];
    __syncthreads();
  }
  if (s == 0) out[0] = -part[0] / (float)NEOUT;
}

extern "C" void kernel_launch(void* const* d_in, const int* in_sizes, int n_in,
                              void* d_out, int out_size, void* d_ws, size_t ws_size,
                              hipStream_t stream) {
  const float* A      = (const float*)d_in[0];
  const int*   edges  = (const int*)d_in[1];
  const int*   attidx = (const int*)d_in[2];
  const int*   nif    = (const int*)d_in[3];
  const int*   cl     = (const int*)d_in[4];
  const int*   nig    = (const int*)d_in[5];
  const float* label  = (const float*)d_in[6];
  const int*   subidx = (const int*)d_in[7];
  const float* Wdec   = (const float*)d_in[8];
  const float* bdec   = (const float*)d_in[9];
  const float* cemb   = (const float*)d_in[10];
  const float* Wm1    = (const float*)d_in[11];
  const float* bm1    = (const float*)d_in[12];
  const float* Wm2    = (const float*)d_in[13];
  const float* bm2    = (const float*)d_in[14];
  const float* Wa1    = (const float*)d_in[15];
  const float* ba1    = (const float*)d_in[16];
  const float* Wa2    = (const float*)d_in[17];
  const float* ba2    = (const float*)d_in[18];
  const float* Wih    = (const float*)d_in[19];
  const float* bih    = (const float*)d_in[20];
  const float* Whh    = (const float*)d_in[21];
  const float* bhh    = (const float*)d_in[22];
  const float* Wt1    = (const float*)d_in[23];
  const float* bt1    = (const float*)d_in[24];
  const float* Wt2    = (const float*)d_in[25];
  const float* bt2    = (const float*)d_in[26];
  const float* Wt3    = (const float*)d_in[27];
  const float* bt3    = (const float*)d_in[28];
  const float* Wha1   = (const float*)d_in[29];
  const float* hba1   = (const float*)d_in[30];
  const float* Wha2   = (const float*)d_in[31];
  const float* hba2   = (const float*)d_in[32];
  const float* Wha3   = (const float*)d_in[33];
  const float* hba3   = (const float*)d_in[34];

  char* ws = (char*)d_ws;
  const size_t SZ_STATE = (size_t)NGNN * DDIM * sizeof(float);   // 25.2 MB
  float* state     = (float*)ws;
  float* agg       = (float*)(ws + SZ_STATE);
  float* nf        = agg;  // decode output lives where agg will go (dead before first memset)
  float* red_loss  = (float*)(ws + 2 * SZ_STATE);
  float* red_alpha = red_loss + NSUB * KMIX;
  float* cnt       = red_alpha + NSUB * KMIX;
  short* pk        = (short*)(ws + 2 * SZ_STATE + (((size_t)(2 * NSUB * KMIX + NSUB) * 4 + 255) / 256) * 256);
  short* pWm1  = pk;             // 6*12*512
  short* pWa1e = pWm1  + 36864;  // 6*8*512
  short* pWm2  = pWa1e + 24576;  // 6*12*512
  short* pWa2e = pWm2  + 36864;  // 4*12*512
  short* pWt1  = pWa2e + 24576;  // 6*8*512
  short* pWt2  = pWt1  + 24576;  // 4*8*512
  short* pWt3  = pWt2  + 16384;  // 4*2*512
  short* pWh1  = pWt3  + 4096;   // 6*8*512
  short* pWh2  = pWh1  + 24576;  // 4*8*512
  short* pWh3  = pWh2  + 16384;  // 4*2*512

  // pack weights to bf16 B-fragment layout (K must be mult of 32: grid = (K/32)*CT)
  k_pack<<<72, 64, 0, stream>>>(Wm1,  pWm1,  192, 12);
  k_pack<<<48, 64, 0, stream>>>(Wa1,  pWa1e, 128, 8);
  k_pack<<<72, 64, 0, stream>>>(Wm2,  pWm2,  192, 12);
  k_pack<<<48, 64, 0, stream>>>(Wa2,  pWa2e, 192, 12);
  k_pack<<<48, 64, 0, stream>>>(Wt1,  pWt1,  128, 8);
  k_pack<<<32, 64, 0, stream>>>(Wt2,  pWt2,  128, 8);
  k_pack<<< 8, 64, 0, stream>>>(Wt3,  pWt3,   20, 2);
  k_pack<<<48, 64, 0, stream>>>(Wha1, pWh1,  128, 8);
  k_pack<<<32, 64, 0, stream>>>(Wha2, pWh2,  128, 8);
  k_pack<<< 8, 64, 0, stream>>>(Wha3, pWh3,   20, 2);

  k_dec<<<NGNN, 128, 0, stream>>>(A, Wdec, bdec, nf);
  k_state<<<NGNN, 192, 0, stream>>>(nf, cemb, nif, cl, state);
  for (int p = 0; p < 2; p++) {
    hipMemsetAsync(agg, 0, SZ_STATE, stream);
    k_edge_mfma<<<NEDGE / 32, 128, 0, stream>>>(state, edges, attidx,
        Wm1, bm1, pWm1, pWm2, bm2, Wa1, ba1, pWa1e, pWa2e, ba2, agg);
    k_gru<<<NGNN / GN, 192, 0, stream>>>(state, agg, Wih, bih, Whh, bhh);
  }
  hipMemsetAsync(red_loss, 0, (size_t)(2 * NSUB * KMIX + NSUB) * sizeof(float), stream);
  k_head_mfma<<<(NEOUT + 63) / 64, 256, 0, stream>>>(state, nig, label, subidx,
      pWt1, bt1, pWt2, bt2, pWt3, bt3, pWh1, hba1, pWh2, hba2, pWh3, hba3,
      red_loss, red_alpha, cnt);
  k_final<<<1, 1024, 0, stream>>>(red_loss, red_alpha, cnt, (float*)d_out);
}

// Round 3
// 1058.744 us; speedup vs baseline: 3.7645x; 1.4361x over previous
//
#include <hip/hip_runtime.h>
#include <math.h>

#define NGNN   32768
#define NMAXD  1024
#define HIDD   128
#define CLSD   64
#define DDIM   192
#define ATTH   128
#define NEDGE  200000
#define NEOUT  500000
#define NSUB   1024
#define KMIX   20

typedef __attribute__((ext_vector_type(8))) short bf16x8;
typedef __attribute__((ext_vector_type(4))) float f32x4;

__device__ __forceinline__ float sigm(float x) { return 1.0f / (1.0f + __expf(-x)); }
__device__ __forceinline__ float tanhf_(float x) { return 2.0f / (1.0f + __expf(-2.0f * x)) - 1.0f; }

__device__ __forceinline__ short f2bf(float f) {
  union { float f; unsigned u; } v; v.f = f;
  unsigned r = v.u + 0x7FFFu + ((v.u >> 16) & 1u);
  return (short)(r >> 16);
}

__device__ __forceinline__ f32x4 bc4(float b) {
  f32x4 v; v[0] = b; v[1] = b; v[2] = b; v[3] = b; return v;
}

// ---------------- pack fp32 [K][N] weight into bf16 MFMA B-fragment order:
// out[((ks*CT+ct)*64 + l)*8 + j] = W[(ks*32 + (l>>4)*8 + j)][ct*16 + (l&15)]  (0 if col>=N)
__global__ __launch_bounds__(64) void k_pack(const float* __restrict__ W,
                                             short* __restrict__ out, int N, int CT) {
  const int l = threadIdx.x;
  const int ks = blockIdx.x / CT;
  const int ct = blockIdx.x % CT;
  const int row0 = ks * 32 + (l >> 4) * 8;
  const int col = ct * 16 + (l & 15);
  short v[8];
#pragma unroll
  for (int j = 0; j < 8; j++) {
    const float f = (col < N) ? W[(size_t)(row0 + j) * N + col] : 0.0f;
    v[j] = f2bf(f);
  }
  *(bf16x8*)(out + ((size_t)blockIdx.x * 64 + l) * 8) = *(bf16x8*)v;
}

// ---------------- nf = A @ W_dec + b_dec, exploiting A in {0,1} with ~5% density
__global__ __launch_bounds__(128) void k_dec(
    const float* __restrict__ A, const float* __restrict__ Wd,
    const float* __restrict__ bd, float* __restrict__ nf) {
  __shared__ float arow[NMAXD];
  __shared__ int   nz[NMAXD];
  __shared__ int   cnt;
  const int row = blockIdx.x;
  const int t = threadIdx.x;
  if (t == 0) cnt = 0;
  const float4* A4 = (const float4*)(A + (size_t)row * NMAXD);
  float4* a4 = (float4*)arow;
  a4[t] = A4[t];
  a4[t + 128] = A4[t + 128];
  __syncthreads();
  for (int i = t; i < NMAXD; i += 128) {
    if (arow[i] != 0.0f) {
      int p = atomicAdd(&cnt, 1);
      nz[p] = i;
    }
  }
  __syncthreads();
  float acc = bd[t];
  const int n = cnt;
  for (int i = 0; i < n; i++) acc += Wd[(size_t)nz[i] * HIDD + t];
  nf[(size_t)row * HIDD + t] = acc;
}

// ---------------- state[i] = concat(nf[nif[i]] (0-row aware), class_emb[cl[i]])
__global__ __launch_bounds__(192) void k_state(
    const float* __restrict__ nf, const float* __restrict__ cemb,
    const int* __restrict__ nif, const int* __restrict__ cl,
    float* __restrict__ state) {
  const int i = blockIdx.x;
  const int t = threadIdx.x;
  float v;
  if (t < HIDD) {
    const int idx = nif[i];
    v = (idx == 0) ? 0.0f : nf[(size_t)(idx - 1) * HIDD + t];
  } else {
    v = cemb[cl[i] * CLSD + (t - HIDD)];
  }
  state[(size_t)i * DDIM + t] = v;
}

// ---------------- MFMA edge kernel: 32 edges/block, 128 threads (2 waves)
__global__ __launch_bounds__(128, 2) void k_edge_mfma(
    const float* __restrict__ state, const int* __restrict__ edges,
    const int* __restrict__ attidx,
    const float* __restrict__ Wm1, const float* __restrict__ bm1,
    const short* __restrict__ pWm1, const short* __restrict__ pWm2,
    const float* __restrict__ bm2,
    const float* __restrict__ Wa1, const float* __restrict__ ba1,
    const short* __restrict__ pWa1, const short* __restrict__ pWa2,
    const float* __restrict__ ba2,
    float* __restrict__ agg) {
  __shared__ short pdiff[6144];  // [rt<2][ks<6][lane<64][8]  K=192 A-frags
  __shared__ short phm[6144];    // hm A-frags (K=192)
  __shared__ short pha[4096];    // ha A-frags (K=128)
  const int t = threadIdx.x;
  const int e0 = blockIdx.x * 32;

  // stage diff -> pdiff in A-fragment order
  for (int it = 0; it < 6; it++) {
    const int id = t + 128 * it;      // 768 tasks: 32 rows x 24 col-groups
    const int r = id / 24, g24 = id % 24;
    const int e = e0 + r;
    const int s = edges[2 * e], d = edges[2 * e + 1];
    const float4 a0 = *(const float4*)&state[(size_t)s * DDIM + g24 * 8];
    const float4 a1 = *(const float4*)&state[(size_t)s * DDIM + g24 * 8 + 4];
    const float4 b0 = *(const float4*)&state[(size_t)d * DDIM + g24 * 8];
    const float4 b1 = *(const float4*)&state[(size_t)d * DDIM + g24 * 8 + 4];
    short s8[8];
    s8[0] = f2bf(a0.x - b0.x); s8[1] = f2bf(a0.y - b0.y);
    s8[2] = f2bf(a0.z - b0.z); s8[3] = f2bf(a0.w - b0.w);
    s8[4] = f2bf(a1.x - b1.x); s8[5] = f2bf(a1.y - b1.y);
    s8[6] = f2bf(a1.z - b1.z); s8[7] = f2bf(a1.w - b1.w);
    const int rt = r >> 4, ks = g24 >> 2, g = g24 & 3;
    *(bf16x8*)&pdiff[((rt * 6 + ks) * 64 + g * 16 + (r & 15)) * 8] = *(bf16x8*)s8;
  }

  const int wid = t >> 6, l = t & 63;
  const int col16 = l & 15, rr = (l >> 4) * 4;
  // per-lane metadata for its 4 output rows
  int a0r[4], a1r[4], dstr[4];
#pragma unroll
  for (int j = 0; j < 4; j++) {
    const int e = e0 + wid * 16 + rr + j;
    const int s = edges[2 * e], d = edges[2 * e + 1];
    a0r[j] = attidx[s]; a1r[j] = attidx[d]; dstr[j] = d;
  }
  __syncthreads();

  // msg L1: [32x192]@[192x192], one-hot part via fp32 gathers into acc init
  for (int ct = 0; ct < 12; ct++) {
    const int col = ct * 16 + col16;
    f32x4 acc;
#pragma unroll
    for (int j = 0; j < 4; j++)
      acc[j] = bm1[col] + Wm1[(size_t)(DDIM + a0r[j]) * DDIM + col]
                        + Wm1[(size_t)(DDIM + 64 + a1r[j]) * DDIM + col];
    for (int ks = 0; ks < 6; ks++) {
      bf16x8 a = *(const bf16x8*)&pdiff[((wid * 6 + ks) * 64 + l) * 8];
      bf16x8 b = *(const bf16x8*)&pWm1[((ks * 12 + ct) * 64 + l) * 8];
      acc = __builtin_amdgcn_mfma_f32_16x16x32_bf16(a, b, acc, 0, 0, 0);
    }
    const int ksp = col >> 5, gp = (col & 31) >> 3, jp = col & 7;
#pragma unroll
    for (int j = 0; j < 4; j++)
      phm[((wid * 6 + ksp) * 64 + gp * 16 + rr + j) * 8 + jp] = f2bf(fmaxf(acc[j], 0.0f));
  }
  // att L1: [32x192]@[192x128]
  for (int ct = 0; ct < 8; ct++) {
    const int col = ct * 16 + col16;
    f32x4 acc;
#pragma unroll
    for (int j = 0; j < 4; j++)
      acc[j] = ba1[col] + Wa1[(size_t)(DDIM + a0r[j]) * ATTH + col]
                        + Wa1[(size_t)(DDIM + 64 + a1r[j]) * ATTH + col];
    for (int ks = 0; ks < 6; ks++) {
      bf16x8 a = *(const bf16x8*)&pdiff[((wid * 6 + ks) * 64 + l) * 8];
      bf16x8 b = *(const bf16x8*)&pWa1[((ks * 8 + ct) * 64 + l) * 8];
      acc = __builtin_amdgcn_mfma_f32_16x16x32_bf16(a, b, acc, 0, 0, 0);
    }
    const int ksp = ct >> 1, gp = ((ct & 1) * 16 + col16) >> 3, jp = col16 & 7;
#pragma unroll
    for (int j = 0; j < 4; j++)
      pha[((wid * 4 + ksp) * 64 + gp * 16 + rr + j) * 8 + jp] = f2bf(fmaxf(acc[j], 0.0f));
  }
  __syncthreads();

  // L2 (msg: K=192, att: K=128, both N=192), combine msg*sigm(att), scatter-add
  for (int ct = 0; ct < 12; ct++) {
    const int col = ct * 16 + col16;
    f32x4 m, av;
    const float bm = bm2[col], ba = ba2[col];
    m[0] = bm; m[1] = bm; m[2] = bm; m[3] = bm;
    av[0] = ba; av[1] = ba; av[2] = ba; av[3] = ba;
    for (int ks = 0; ks < 6; ks++) {
      bf16x8 a = *(const bf16x8*)&phm[((wid * 6 + ks) * 64 + l) * 8];
      bf16x8 b = *(const bf16x8*)&pWm2[((ks * 12 + ct) * 64 + l) * 8];
      m = __builtin_amdgcn_mfma_f32_16x16x32_bf16(a, b, m, 0, 0, 0);
    }
    for (int ks = 0; ks < 4; ks++) {
      bf16x8 a = *(const bf16x8*)&pha[((wid * 4 + ks) * 64 + l) * 8];
      bf16x8 b = *(const bf16x8*)&pWa2[((ks * 12 + ct) * 64 + l) * 8];
      av = __builtin_amdgcn_mfma_f32_16x16x32_bf16(a, b, av, 0, 0, 0);
    }
#pragma unroll
    for (int j = 0; j < 4; j++) {
      atomicAdd(&agg[(size_t)dstr[j] * DDIM + col], m[j] * sigm(av[j]));
    }
  }
}

// ---------------- MFMA GRU: 64 nodes/block, 256 threads (4 waves)
// gi = agg@W_ih+b_ih, gh = state@W_hh+b_hh; for output col c the gate needs
// (c, c+192, c+384) of gi and gh -> same lane at ct, ct+12, ct+24 -> gating
// is register-local. In-place state update; each lane reads exactly the fp32
// elements it later writes (rows owned by this block only).
__global__ __launch_bounds__(256, 2) void k_gru_mfma(
    float* __restrict__ state, const float* __restrict__ agg,
    const short* __restrict__ pWih, const float* __restrict__ bih,
    const short* __restrict__ pWhh, const float* __restrict__ bhh) {
  __shared__ short pagg[12288];   // [rt<4][ks<6][64][8]
  __shared__ short pst[12288];
  const int t = threadIdx.x;
  const int n0 = blockIdx.x * 64;

  for (int it = 0; it < 6; it++) {
    const int id = t + 256 * it;      // 1536 tasks: 64 rows x 24 col-groups
    const int r = id / 24, g24 = id % 24;
    const size_t base = (size_t)(n0 + r) * DDIM + g24 * 8;
    const float4 a0 = *(const float4*)&agg[base];
    const float4 a1 = *(const float4*)&agg[base + 4];
    const float4 s0 = *(const float4*)&state[base];
    const float4 s1 = *(const float4*)&state[base + 4];
    short va[8], vs[8];
    va[0] = f2bf(a0.x); va[1] = f2bf(a0.y); va[2] = f2bf(a0.z); va[3] = f2bf(a0.w);
    va[4] = f2bf(a1.x); va[5] = f2bf(a1.y); va[6] = f2bf(a1.z); va[7] = f2bf(a1.w);
    vs[0] = f2bf(s0.x); vs[1] = f2bf(s0.y); vs[2] = f2bf(s0.z); vs[3] = f2bf(s0.w);
    vs[4] = f2bf(s1.x); vs[5] = f2bf(s1.y); vs[6] = f2bf(s1.z); vs[7] = f2bf(s1.w);
    const int rt = r >> 4, ks = g24 >> 2, g = g24 & 3;
    const int off = ((rt * 6 + ks) * 64 + g * 16 + (r & 15)) * 8;
    *(bf16x8*)&pagg[off] = *(bf16x8*)va;
    *(bf16x8*)&pst[off]  = *(bf16x8*)vs;
  }
  __syncthreads();

  const int wid = t >> 6, l = t & 63;
  const int col16 = l & 15, rr = (l >> 4) * 4;
  bf16x8 af[6], sf[6];
#pragma unroll
  for (int ks = 0; ks < 6; ks++) {
    af[ks] = *(const bf16x8*)&pagg[((wid * 6 + ks) * 64 + l) * 8];
    sf[ks] = *(const bf16x8*)&pst[((wid * 6 + ks) * 64 + l) * 8];
  }

  for (int ct = 0; ct < 12; ct++) {
    const int c = ct * 16 + col16;
    f32x4 ir = bc4(bih[c]), iz = bc4(bih[c + DDIM]), in_ = bc4(bih[c + 2 * DDIM]);
    f32x4 hr = bc4(bhh[c]), hz = bc4(bhh[c + DDIM]), hn = bc4(bhh[c + 2 * DDIM]);
#pragma unroll
    for (int ks = 0; ks < 6; ks++) {
      const bf16x8 wr = *(const bf16x8*)&pWih[((size_t)(ks * 36 + ct) * 64 + l) * 8];
      const bf16x8 wz = *(const bf16x8*)&pWih[((size_t)(ks * 36 + ct + 12) * 64 + l) * 8];
      const bf16x8 wn = *(const bf16x8*)&pWih[((size_t)(ks * 36 + ct + 24) * 64 + l) * 8];
      ir  = __builtin_amdgcn_mfma_f32_16x16x32_bf16(af[ks], wr, ir, 0, 0, 0);
      iz  = __builtin_amdgcn_mfma_f32_16x16x32_bf16(af[ks], wz, iz, 0, 0, 0);
      in_ = __builtin_amdgcn_mfma_f32_16x16x32_bf16(af[ks], wn, in_, 0, 0, 0);
      const bf16x8 vr = *(const bf16x8*)&pWhh[((size_t)(ks * 36 + ct) * 64 + l) * 8];
      const bf16x8 vz = *(const bf16x8*)&pWhh[((size_t)(ks * 36 + ct + 12) * 64 + l) * 8];
      const bf16x8 vn = *(const bf16x8*)&pWhh[((size_t)(ks * 36 + ct + 24) * 64 + l) * 8];
      hr = __builtin_amdgcn_mfma_f32_16x16x32_bf16(sf[ks], vr, hr, 0, 0, 0);
      hz = __builtin_amdgcn_mfma_f32_16x16x32_bf16(sf[ks], vz, hz, 0, 0, 0);
      hn = __builtin_amdgcn_mfma_f32_16x16x32_bf16(sf[ks], vn, hn, 0, 0, 0);
    }
#pragma unroll
    for (int j = 0; j < 4; j++) {
      const size_t idx = (size_t)(n0 + wid * 16 + rr + j) * DDIM + c;
      const float sv = state[idx];
      const float r = sigm(ir[j] + hr[j]);
      const float z = sigm(iz[j] + hz[j]);
      const float nn = tanhf_(in_[j] + r * hn[j]);
      state[idx] = (1.0f - z) * nn + z * sv;
    }
  }
}

// ---------------- MFMA head: 64 rows/block, 256 threads (4 waves)
__device__ __forceinline__ void head_branch(
    const short* pd, short* ph1, short* ph2,
    const short* __restrict__ pW1, const float* __restrict__ b1,
    const short* __restrict__ pW2, const float* __restrict__ b2,
    const short* __restrict__ pW3, const float* __restrict__ b3,
    int wid, int l, f32x4 out3[2]) {
  const int col16 = l & 15, rr = (l >> 4) * 4;
  // L1: K=192, N=128
  for (int ct = 0; ct < 8; ct++) {
    const int col = ct * 16 + col16;
    f32x4 acc;
    const float bb = b1[col];
    acc[0] = bb; acc[1] = bb; acc[2] = bb; acc[3] = bb;
    for (int ks = 0; ks < 6; ks++) {
      bf16x8 a = *(const bf16x8*)&pd[((wid * 6 + ks) * 64 + l) * 8];
      bf16x8 b = *(const bf16x8*)&pW1[((ks * 8 + ct) * 64 + l) * 8];
      acc = __builtin_amdgcn_mfma_f32_16x16x32_bf16(a, b, acc, 0, 0, 0);
    }
    const int ksp = ct >> 1, gp = ((ct & 1) * 16 + col16) >> 3, jp = col16 & 7;
#pragma unroll
    for (int j = 0; j < 4; j++)
      ph1[((wid * 4 + ksp) * 64 + gp * 16 + rr + j) * 8 + jp] = f2bf(fmaxf(acc[j], 0.0f));
  }
  __syncthreads();
  // L2: K=128, N=128
  for (int ct = 0; ct < 8; ct++) {
    const int col = ct * 16 + col16;
    f32x4 acc;
    const float bb = b2[col];
    acc[0] = bb; acc[1] = bb; acc[2] = bb; acc[3] = bb;
    for (int ks = 0; ks < 4; ks++) {
      bf16x8 a = *(const bf16x8*)&ph1[((wid * 4 + ks) * 64 + l) * 8];
      bf16x8 b = *(const bf16x8*)&pW2[((ks * 8 + ct) * 64 + l) * 8];
      acc = __builtin_amdgcn_mfma_f32_16x16x32_bf16(a, b, acc, 0, 0, 0);
    }
    const int ksp = ct >> 1, gp = ((ct & 1) * 16 + col16) >> 3, jp = col16 & 7;
#pragma unroll
    for (int j = 0; j < 4; j++)
      ph2[((wid * 4 + ksp) * 64 + gp * 16 + rr + j) * 8 + jp] = f2bf(fmaxf(acc[j], 0.0f));
  }
  __syncthreads();
  // L3: K=128, N=32 (cols >= 20 are zero-padded in pW3)
  for (int ct = 0; ct < 2; ct++) {
    const int col = ct * 16 + col16;
    f32x4 acc;
    const float bb = (col < KMIX) ? b3[col] : 0.0f;
    acc[0] = bb; acc[1] = bb; acc[2] = bb; acc[3] = bb;
    for (int ks = 0; ks < 4; ks++) {
      bf16x8 a = *(const bf16x8*)&ph2[((wid * 4 + ks) * 64 + l) * 8];
      bf16x8 b = *(const bf16x8*)&pW3[((ks * 2 + ct) * 64 + l) * 8];
      acc = __builtin_amdgcn_mfma_f32_16x16x32_bf16(a, b, acc, 0, 0, 0);
    }
    out3[ct] = acc;
  }
}

__global__ __launch_bounds__(256, 2) void k_head_mfma(
    const float* __restrict__ state, const int* __restrict__ nig,
    const float* __restrict__ label, const int* __restrict__ subidx,
    const short* __restrict__ pWt1, const float* __restrict__ bt1,
    const short* __restrict__ pWt2, const float* __restrict__ bt2,
    const short* __restrict__ pWt3, const float* __restrict__ bt3,
    const short* __restrict__ pWa1, const float* __restrict__ ba1,
    const short* __restrict__ pWa2, const float* __restrict__ ba2,
    const short* __restrict__ pWa3, const float* __restrict__ ba3,
    float* __restrict__ red_loss, float* __restrict__ red_alpha,
    float* __restrict__ cnt) {
  __shared__ short pd[12288];   // dout A-frags [rt<4][ks<6][64][8]
  __shared__ short ph1[8192];   // [rt<4][ks<4][64][8]
  __shared__ short ph2[8192];
  __shared__ int   ssub[64];
  __shared__ float slab[64];
  __shared__ float lse[64];
  float* la = (float*)pd;       // [64][20] overlay; first write is after last pd read

  const int t = threadIdx.x;
  const int r0 = blockIdx.x * 64;

  if (t < 64) {
    const int gr = r0 + t;
    const int sb = (gr < NEOUT) ? subidx[gr] : 0;
    ssub[t] = sb;
    slab[t] = (gr < NEOUT) ? label[gr] : 0.0f;
    if (gr < NEOUT) atomicAdd(&cnt[sb], 1.0f);
  }
  for (int it = 0; it < 6; it++) {
    const int id = t + 256 * it;      // 1536 tasks: 64 rows x 24 col-groups
    const int r = id / 24, g24 = id % 24;
    const int gr = r0 + r;
    float v[8];
    if (gr < NEOUT) {
      const int ia = nig[2 * gr], ib = nig[2 * gr + 1];
      const float4 a0 = *(const float4*)&state[(size_t)ia * DDIM + g24 * 8];
      const float4 a1 = *(const float4*)&state[(size_t)ia * DDIM + g24 * 8 + 4];
      const float4 b0 = *(const float4*)&state[(size_t)ib * DDIM + g24 * 8];
      const float4 b1 = *(const float4*)&state[(size_t)ib * DDIM + g24 * 8 + 4];
      v[0] = a0.x - b0.x; v[1] = a0.y - b0.y; v[2] = a0.z - b0.z; v[3] = a0.w - b0.w;
      v[4] = a1.x - b1.x; v[5] = a1.y - b1.y; v[6] = a1.z - b1.z; v[7] = a1.w - b1.w;
    } else {
#pragma unroll
      for (int j = 0; j < 8; j++) v[j] = 0.0f;
    }
    short s8[8];
#pragma unroll
    for (int j = 0; j < 8; j++) s8[j] = f2bf(v[j]);
    const int rt = r >> 4, ks = g24 >> 2, g = g24 & 3;
    *(bf16x8*)&pd[((rt * 6 + ks) * 64 + g * 16 + (r & 15)) * 8] = *(bf16x8*)s8;
  }
  __syncthreads();

  const int wid = t >> 6, l = t & 63;
  const int col16 = l & 15, rr = (l >> 4) * 4;
  f32x4 out3[2];

  // ---- theta ----
  head_branch(pd, ph1, ph2, pWt1, bt1, pWt2, bt2, pWt3, bt3, wid, l, out3);
#pragma unroll
  for (int ct = 0; ct < 2; ct++) {
    const int col = ct * 16 + col16;
    if (col < KMIX) {
#pragma unroll
      for (int j = 0; j < 4; j++) {
        const int r = wid * 16 + rr + j;
        if (r0 + r < NEOUT) {
          const float lt = out3[ct][j];
          const float adj = fmaxf(lt, 0.0f) + logf(1.0f + __expf(-fabsf(lt))) - lt * slab[r];
          atomicAdd(&red_loss[ssub[r] * KMIX + col], adj);
        }
      }
    }
  }
  // ---- alpha ----
  head_branch(pd, ph1, ph2, pWa1, ba1, pWa2, ba2, pWa3, ba3, wid, l, out3);
#pragma unroll
  for (int ct = 0; ct < 2; ct++) {
    const int col = ct * 16 + col16;
    if (col < KMIX) {
#pragma unroll
      for (int j = 0; j < 4; j++) {
        const int r = wid * 16 + rr + j;
        la[r * KMIX + col] = out3[ct][j];
      }
    }
  }
  __syncthreads();
  if (t < 64) {
    float m = -1e30f;
    for (int k = 0; k < KMIX; k++) m = fmaxf(m, la[t * KMIX + k]);
    float s = 0.0f;
    for (int k = 0; k < KMIX; k++) s += __expf(la[t * KMIX + k] - m);
    lse[t] = m + logf(s);
  }
  __syncthreads();
  {
    const int r = t >> 2;
    if (r0 + r < NEOUT) {
      for (int i = 0; i < 5; i++) {
        const int c = (t & 3) + 4 * i;
        atomicAdd(&red_alpha[ssub[r] * KMIX + c], la[r * KMIX + c] - lse[r]);
      }
    }
  }
}

// ---------------- final: per-subgraph logsumexp, reduce to scalar
__global__ __launch_bounds__(1024) void k_final(
    const float* __restrict__ red_loss, const float* __restrict__ red_alpha,
    const float* __restrict__ cnt, float* __restrict__ out) {
  __shared__ float part[1024];
  const int s = threadIdx.x;
  const float c = fmaxf(cnt[s], 1.0f);
  float v[KMIX];
  float m = -1e30f;
  for (int k = 0; k < KMIX; k++) {
    v[k] = -red_loss[s * KMIX + k] + red_alpha[s * KMIX + k] / c;
    m = fmaxf(m, v[k]);
  }
  float sum = 0.0f;
  for (int k = 0; k < KMIX; k++) sum += __expf(v[k] - m);
  part[s] = m + logf(sum);
  __syncthreads();
  for (int st = 512; st > 0; st >>= 1) {
    if (s < st) part[s] += part[s + st];
    __syncthreads();
  }
  if (s == 0) out[0] = -part[0] / (float)NEOUT;
}

extern "C" void kernel_launch(void* const* d_in, const int* in_sizes, int n_in,
                              void* d_out, int out_size, void* d_ws, size_t ws_size,
                              hipStream_t stream) {
  const float* A      = (const float*)d_in[0];
  const int*   edges  = (const int*)d_in[1];
  const int*   attidx = (const int*)d_in[2];
  const int*   nif    = (const int*)d_in[3];
  const int*   cl     = (const int*)d_in[4];
  const int*   nig    = (const int*)d_in[5];
  const float* label  = (const float*)d_in[6];
  const int*   subidx = (const int*)d_in[7];
  const float* Wdec   = (const float*)d_in[8];
  const float* bdec   = (const float*)d_in[9];
  const float* cemb   = (const float*)d_in[10];
  const float* Wm1    = (const float*)d_in[11];
  const float* bm1    = (const float*)d_in[12];
  const float* Wm2    = (const float*)d_in[13];
  const float* bm2    = (const float*)d_in[14];
  const float* Wa1    = (const float*)d_in[15];
  const float* ba1    = (const float*)d_in[16];
  const float* Wa2    = (const float*)d_in[17];
  const float* ba2    = (const float*)d_in[18];
  const float* Wih    = (const float*)d_in[19];
  const float* bih    = (const float*)d_in[20];
  const float* Whh    = (const float*)d_in[21];
  const float* bhh    = (const float*)d_in[22];
  const float* Wt1    = (const float*)d_in[23];
  const float* bt1    = (const float*)d_in[24];
  const float* Wt2    = (const float*)d_in[25];
  const float* bt2    = (const float*)d_in[26];
  const float* Wt3    = (const float*)d_in[27];
  const float* bt3    = (const float*)d_in[28];
  const float* Wha1   = (const float*)d_in[29];
  const float* hba1   = (const float*)d_in[30];
  const float* Wha2   = (const float*)d_in[31];
  const float* hba2   = (const float*)d_in[32];
  const float* Wha3   = (const float*)d_in[33];
  const float* hba3   = (const float*)d_in[34];

  char* ws = (char*)d_ws;
  const size_t SZ_STATE = (size_t)NGNN * DDIM * sizeof(float);   // 25.2 MB
  float* state     = (float*)ws;
  float* agg       = (float*)(ws + SZ_STATE);
  float* nf        = agg;  // decode output lives where agg will go (dead before first memset)
  float* red_loss  = (float*)(ws + 2 * SZ_STATE);
  float* red_alpha = red_loss + NSUB * KMIX;
  float* cnt       = red_alpha + NSUB * KMIX;
  short* pk        = (short*)(ws + 2 * SZ_STATE + (((size_t)(2 * NSUB * KMIX + NSUB) * 4 + 255) / 256) * 256);
  short* pWm1  = pk;             // 6*12*512
  short* pWa1e = pWm1  + 36864;  // 6*8*512
  short* pWm2  = pWa1e + 24576;  // 6*12*512
  short* pWa2e = pWm2  + 36864;  // 4*12*512
  short* pWt1  = pWa2e + 24576;  // 6*8*512
  short* pWt2  = pWt1  + 24576;  // 4*8*512
  short* pWt3  = pWt2  + 16384;  // 4*2*512
  short* pWh1  = pWt3  + 4096;   // 6*8*512
  short* pWh2  = pWh1  + 24576;  // 4*8*512
  short* pWh3  = pWh2  + 16384;  // 4*2*512
  short* pWih  = pWh3  + 4096;   // 6*36*512
  short* pWhh  = pWih  + 110592; // 6*36*512

  // pack weights to bf16 B-fragment layout (grid = (K/32)*CT)
  k_pack<<<72, 64, 0, stream>>>(Wm1,  pWm1,  192, 12);
  k_pack<<<48, 64, 0, stream>>>(Wa1,  pWa1e, 128, 8);
  k_pack<<<72, 64, 0, stream>>>(Wm2,  pWm2,  192, 12);
  k_pack<<<48, 64, 0, stream>>>(Wa2,  pWa2e, 192, 12);
  k_pack<<<48, 64, 0, stream>>>(Wt1,  pWt1,  128, 8);
  k_pack<<<32, 64, 0, stream>>>(Wt2,  pWt2,  128, 8);
  k_pack<<< 8, 64, 0, stream>>>(Wt3,  pWt3,   20, 2);
  k_pack<<<48, 64, 0, stream>>>(Wha1, pWh1,  128, 8);
  k_pack<<<32, 64, 0, stream>>>(Wha2, pWh2,  128, 8);
  k_pack<<< 8, 64, 0, stream>>>(Wha3, pWh3,   20, 2);
  k_pack<<<216, 64, 0, stream>>>(Wih, pWih,  576, 36);
  k_pack<<<216, 64, 0, stream>>>(Whh, pWhh,  576, 36);

  k_dec<<<NGNN, 128, 0, stream>>>(A, Wdec, bdec, nf);
  k_state<<<NGNN, 192, 0, stream>>>(nf, cemb, nif, cl, state);
  for (int p = 0; p < 2; p++) {
    hipMemsetAsync(agg, 0, SZ_STATE, stream);
    k_edge_mfma<<<NEDGE / 32, 128, 0, stream>>>(state, edges, attidx,
        Wm1, bm1, pWm1, pWm2, bm2, Wa1, ba1, pWa1e, pWa2e, ba2, agg);
    k_gru_mfma<<<NGNN / 64, 256, 0, stream>>>(state, agg, pWih, bih, pWhh, bhh);
  }
  hipMemsetAsync(red_loss, 0, (size_t)(2 * NSUB * KMIX + NSUB) * sizeof(float), stream);
  k_head_mfma<<<(NEOUT + 63) / 64, 256, 0, stream>>>(state, nig, label, subidx,
      pWt1, bt1, pWt2, bt2, pWt3, bt3, pWh1, hba1, pWh2, hba2, pWh3, hba3,
      red_loss, red_alpha, cnt);
  k_final<<<1, 1024, 0, stream>>>(red_loss, red_alpha, cnt, (float*)d_out);
}

// Round 4
// 986.647 us; speedup vs baseline: 4.0396x; 1.0731x over previous
//
#include <hip/hip_runtime.h>
#include <math.h>

#define NGNN   32768
#define NMAXD  1024
#define HIDD   128
#define CLSD   64
#define DDIM   192
#define ATTH   128
#define NEDGE  200000
#define NEOUT  500000
#define NSUB   1024
#define KMIX   20

typedef __attribute__((ext_vector_type(8))) short bf16x8;
typedef __attribute__((ext_vector_type(8))) unsigned short u16x8;
typedef __attribute__((ext_vector_type(4))) float f32x4;

__device__ __forceinline__ float sigm(float x) { return 1.0f / (1.0f + __expf(-x)); }
__device__ __forceinline__ float tanhf_(float x) { return 2.0f / (1.0f + __expf(-2.0f * x)) - 1.0f; }

__device__ __forceinline__ short f2bf(float f) {
  union { float f; unsigned u; } v; v.f = f;
  unsigned r = v.u + 0x7FFFu + ((v.u >> 16) & 1u);
  return (short)(r >> 16);
}
__device__ __forceinline__ float bf2f(unsigned short u) {
  union { unsigned u; float f; } v; v.u = ((unsigned)u) << 16;
  return v.f;
}
__device__ __forceinline__ f32x4 bc4(float b) {
  f32x4 v; v[0] = b; v[1] = b; v[2] = b; v[3] = b; return v;
}

// ---------------- pack fp32 [K][N] weight into bf16 MFMA B-fragment order:
// out[((ks*CT+ct)*64 + l)*8 + j] = W[(ks*32 + (l>>4)*8 + j)][ct*16 + (l&15)]  (0 if col>=N)
__global__ __launch_bounds__(64) void k_pack(const float* __restrict__ W,
                                             short* __restrict__ out, int N, int CT) {
  const int l = threadIdx.x;
  const int ks = blockIdx.x / CT;
  const int ct = blockIdx.x % CT;
  const int row0 = ks * 32 + (l >> 4) * 8;
  const int col = ct * 16 + (l & 15);
  short v[8];
#pragma unroll
  for (int j = 0; j < 8; j++) {
    const float f = (col < N) ? W[(size_t)(row0 + j) * N + col] : 0.0f;
    v[j] = f2bf(f);
  }
  *(bf16x8*)(out + ((size_t)blockIdx.x * 64 + l) * 8) = *(bf16x8*)v;
}

// ---------------- nf = A @ W_dec + b_dec, exploiting A in {0,1} with ~5% density
__global__ __launch_bounds__(128) void k_dec(
    const float* __restrict__ A, const float* __restrict__ Wd,
    const float* __restrict__ bd, float* __restrict__ nf) {
  __shared__ float arow[NMAXD];
  __shared__ int   nz[NMAXD];
  __shared__ int   cnt;
  const int row = blockIdx.x;
  const int t = threadIdx.x;
  if (t == 0) cnt = 0;
  const float4* A4 = (const float4*)(A + (size_t)row * NMAXD);
  float4* a4 = (float4*)arow;
  a4[t] = A4[t];
  a4[t + 128] = A4[t + 128];
  __syncthreads();
  for (int i = t; i < NMAXD; i += 128) {
    if (arow[i] != 0.0f) {
      int p = atomicAdd(&cnt, 1);
      nz[p] = i;
    }
  }
  __syncthreads();
  float acc = bd[t];
  const int n = cnt;
  for (int i = 0; i < n; i++) acc += Wd[(size_t)nz[i] * HIDD + t];
  nf[(size_t)row * HIDD + t] = acc;
}

// ---------------- stbf[i] = bf16(concat(nf[nif[i]] (0-row aware), class_emb[cl[i]]))
__global__ __launch_bounds__(192) void k_state(
    const float* __restrict__ nf, const float* __restrict__ cemb,
    const int* __restrict__ nif, const int* __restrict__ cl,
    unsigned short* __restrict__ stbf) {
  const int i = blockIdx.x;
  const int t = threadIdx.x;
  float v;
  if (t < HIDD) {
    const int idx = nif[i];
    v = (idx == 0) ? 0.0f : nf[(size_t)(idx - 1) * HIDD + t];
  } else {
    v = cemb[cl[i] * CLSD + (t - HIDD)];
  }
  stbf[(size_t)i * DDIM + t] = (unsigned short)f2bf(v);
}

// ---------------- MFMA edge kernel: 32 edges/block, 128 threads (2 waves)
// A-fragments (diff) gathered directly into registers from bf16 state.
__global__ __launch_bounds__(128, 4) void k_edge_mfma(
    const unsigned short* __restrict__ stbf, const int* __restrict__ edges,
    const int* __restrict__ attidx,
    const float* __restrict__ Wm1, const float* __restrict__ bm1,
    const short* __restrict__ pWm1, const short* __restrict__ pWm2,
    const float* __restrict__ bm2,
    const float* __restrict__ Wa1, const float* __restrict__ ba1,
    const short* __restrict__ pWa1, const short* __restrict__ pWa2,
    const float* __restrict__ ba2,
    float* __restrict__ agg) {
  __shared__ short phm[6144];    // hm A-frags (K=192) [wid<2][ks<6][64][8]
  __shared__ short pha[4096];    // ha A-frags (K=128) [wid<2][ks<4][64][8]
  const int t = threadIdx.x;
  const int e0 = blockIdx.x * 32;
  const int wid = t >> 6, l = t & 63;
  const int col16 = l & 15, rr = (l >> 4) * 4;
  const int cb = (l >> 4) * 8;

  // diff A-frags: lane l holds row wid*16+(l&15), k-cols ks*32+cb..+8
  bf16x8 dfrag[6];
  {
    const int e = e0 + wid * 16 + (l & 15);
    const int s = edges[2 * e], d = edges[2 * e + 1];
    const unsigned short* ps = &stbf[(size_t)s * DDIM + cb];
    const unsigned short* pd_ = &stbf[(size_t)d * DDIM + cb];
#pragma unroll
    for (int ks = 0; ks < 6; ks++) {
      const u16x8 a = *(const u16x8*)(ps + ks * 32);
      const u16x8 b = *(const u16x8*)(pd_ + ks * 32);
      short v[8];
#pragma unroll
      for (int j = 0; j < 8; j++) v[j] = f2bf(bf2f(a[j]) - bf2f(b[j]));
      dfrag[ks] = *(bf16x8*)v;
    }
  }
  // per-lane metadata for its 4 output rows
  int a0r[4], a1r[4], dstr[4];
#pragma unroll
  for (int j = 0; j < 4; j++) {
    const int e = e0 + wid * 16 + rr + j;
    const int s = edges[2 * e], d = edges[2 * e + 1];
    a0r[j] = attidx[s]; a1r[j] = attidx[d]; dstr[j] = d;
  }

  // msg L1: [32x192]@[192x192], one-hot part via fp32 gathers into acc init
  for (int ct = 0; ct < 12; ct++) {
    const int col = ct * 16 + col16;
    f32x4 acc;
#pragma unroll
    for (int j = 0; j < 4; j++)
      acc[j] = bm1[col] + Wm1[(size_t)(DDIM + a0r[j]) * DDIM + col]
                        + Wm1[(size_t)(DDIM + 64 + a1r[j]) * DDIM + col];
#pragma unroll
    for (int ks = 0; ks < 6; ks++) {
      bf16x8 b = *(const bf16x8*)&pWm1[((ks * 12 + ct) * 64 + l) * 8];
      acc = __builtin_amdgcn_mfma_f32_16x16x32_bf16(dfrag[ks], b, acc, 0, 0, 0);
    }
    const int ksp = col >> 5, gp = (col & 31) >> 3, jp = col & 7;
#pragma unroll
    for (int j = 0; j < 4; j++)
      phm[((wid * 6 + ksp) * 64 + gp * 16 + rr + j) * 8 + jp] = f2bf(fmaxf(acc[j], 0.0f));
  }
  // att L1: [32x192]@[192x128]
  for (int ct = 0; ct < 8; ct++) {
    const int col = ct * 16 + col16;
    f32x4 acc;
#pragma unroll
    for (int j = 0; j < 4; j++)
      acc[j] = ba1[col] + Wa1[(size_t)(DDIM + a0r[j]) * ATTH + col]
                        + Wa1[(size_t)(DDIM + 64 + a1r[j]) * ATTH + col];
#pragma unroll
    for (int ks = 0; ks < 6; ks++) {
      bf16x8 b = *(const bf16x8*)&pWa1[((ks * 8 + ct) * 64 + l) * 8];
      acc = __builtin_amdgcn_mfma_f32_16x16x32_bf16(dfrag[ks], b, acc, 0, 0, 0);
    }
    const int ksp = ct >> 1, gp = ((ct & 1) * 16 + col16) >> 3, jp = col16 & 7;
#pragma unroll
    for (int j = 0; j < 4; j++)
      pha[((wid * 4 + ksp) * 64 + gp * 16 + rr + j) * 8 + jp] = f2bf(fmaxf(acc[j], 0.0f));
  }
  __syncthreads();

  // L2 (msg: K=192, att: K=128, both N=192), combine msg*sigm(att), scatter-add
  for (int ct = 0; ct < 12; ct++) {
    const int col = ct * 16 + col16;
    f32x4 m = bc4(bm2[col]), av = bc4(ba2[col]);
#pragma unroll
    for (int ks = 0; ks < 6; ks++) {
      bf16x8 a = *(const bf16x8*)&phm[((wid * 6 + ks) * 64 + l) * 8];
      bf16x8 b = *(const bf16x8*)&pWm2[((ks * 12 + ct) * 64 + l) * 8];
      m = __builtin_amdgcn_mfma_f32_16x16x32_bf16(a, b, m, 0, 0, 0);
    }
#pragma unroll
    for (int ks = 0; ks < 4; ks++) {
      bf16x8 a = *(const bf16x8*)&pha[((wid * 4 + ks) * 64 + l) * 8];
      bf16x8 b = *(const bf16x8*)&pWa2[((ks * 12 + ct) * 64 + l) * 8];
      av = __builtin_amdgcn_mfma_f32_16x16x32_bf16(a, b, av, 0, 0, 0);
    }
#pragma unroll
    for (int j = 0; j < 4; j++) {
      atomicAdd(&agg[(size_t)dstr[j] * DDIM + col], m[j] * sigm(av[j]));
    }
  }
}

// ---------------- MFMA GRU: 64 nodes/block, 256 threads (4 waves), zero LDS.
// A-frags for agg (fp32->bf16) and state (bf16) loaded directly into registers;
// gate math is register-local; in-place bf16 state update (wave-owned rows).
__global__ __launch_bounds__(256, 2) void k_gru_mfma(
    unsigned short* __restrict__ stbf, const float* __restrict__ agg,
    const short* __restrict__ pWih, const float* __restrict__ bih,
    const short* __restrict__ pWhh, const float* __restrict__ bhh) {
  const int t = threadIdx.x;
  const int n0 = blockIdx.x * 64;
  const int wid = t >> 6, l = t & 63;
  const int col16 = l & 15, rr = (l >> 4) * 4;
  const int cb = (l >> 4) * 8;
  const int row = n0 + wid * 16 + (l & 15);

  bf16x8 af[6], sf[6];
#pragma unroll
  for (int ks = 0; ks < 6; ks++) {
    const float4 a0 = *(const float4*)&agg[(size_t)row * DDIM + ks * 32 + cb];
    const float4 a1 = *(const float4*)&agg[(size_t)row * DDIM + ks * 32 + cb + 4];
    short v[8];
    v[0] = f2bf(a0.x); v[1] = f2bf(a0.y); v[2] = f2bf(a0.z); v[3] = f2bf(a0.w);
    v[4] = f2bf(a1.x); v[5] = f2bf(a1.y); v[6] = f2bf(a1.z); v[7] = f2bf(a1.w);
    af[ks] = *(bf16x8*)v;
    sf[ks] = *(const bf16x8*)&stbf[(size_t)row * DDIM + ks * 32 + cb];
  }

  for (int ct = 0; ct < 12; ct++) {
    const int c = ct * 16 + col16;
    f32x4 ir = bc4(bih[c]), iz = bc4(bih[c + DDIM]), in_ = bc4(bih[c + 2 * DDIM]);
    f32x4 hr = bc4(bhh[c]), hz = bc4(bhh[c + DDIM]), hn = bc4(bhh[c + 2 * DDIM]);
#pragma unroll
    for (int ks = 0; ks < 6; ks++) {
      const bf16x8 wr = *(const bf16x8*)&pWih[((size_t)(ks * 36 + ct) * 64 + l) * 8];
      const bf16x8 wz = *(const bf16x8*)&pWih[((size_t)(ks * 36 + ct + 12) * 64 + l) * 8];
      const bf16x8 wn = *(const bf16x8*)&pWih[((size_t)(ks * 36 + ct + 24) * 64 + l) * 8];
      ir  = __builtin_amdgcn_mfma_f32_16x16x32_bf16(af[ks], wr, ir, 0, 0, 0);
      iz  = __builtin_amdgcn_mfma_f32_16x16x32_bf16(af[ks], wz, iz, 0, 0, 0);
      in_ = __builtin_amdgcn_mfma_f32_16x16x32_bf16(af[ks], wn, in_, 0, 0, 0);
      const bf16x8 vr = *(const bf16x8*)&pWhh[((size_t)(ks * 36 + ct) * 64 + l) * 8];
      const bf16x8 vz = *(const bf16x8*)&pWhh[((size_t)(ks * 36 + ct + 12) * 64 + l) * 8];
      const bf16x8 vn = *(const bf16x8*)&pWhh[((size_t)(ks * 36 + ct + 24) * 64 + l) * 8];
      hr = __builtin_amdgcn_mfma_f32_16x16x32_bf16(sf[ks], vr, hr, 0, 0, 0);
      hz = __builtin_amdgcn_mfma_f32_16x16x32_bf16(sf[ks], vz, hz, 0, 0, 0);
      hn = __builtin_amdgcn_mfma_f32_16x16x32_bf16(sf[ks], vn, hn, 0, 0, 0);
    }
#pragma unroll
    for (int j = 0; j < 4; j++) {
      const size_t idx = (size_t)(n0 + wid * 16 + rr + j) * DDIM + c;
      const float sv = bf2f(stbf[idx]);
      const float r = sigm(ir[j] + hr[j]);
      const float z = sigm(iz[j] + hz[j]);
      const float nn = tanhf_(in_[j] + r * hn[j]);
      stbf[idx] = (unsigned short)f2bf((1.0f - z) * nn + z * sv);
    }
  }
}

// ---------------- MFMA head: 64 rows/block, 512 threads (8 waves).
// rt = wid&3 row tile (16 rows), ch = wid>>2 column half. Diff A-frags
// in registers; ph1/ph2 LDS for D->A relayout between layers.
__device__ __forceinline__ f32x4 head_branch(
    const bf16x8 dfrag[6], short* ph1, short* ph2,
    const short* __restrict__ pW1, const float* __restrict__ b1,
    const short* __restrict__ pW2, const float* __restrict__ b2,
    const short* __restrict__ pW3, const float* __restrict__ b3,
    int rt, int ch, int l) {
  const int col16 = l & 15, rr = (l >> 4) * 4;
  // L1: K=192, N=128 ; this wave does cols [ch*64, ch*64+64)
  for (int ci = 0; ci < 4; ci++) {
    const int ct = ch * 4 + ci;
    const int col = ct * 16 + col16;
    f32x4 acc = bc4(b1[col]);
#pragma unroll
    for (int ks = 0; ks < 6; ks++) {
      bf16x8 b = *(const bf16x8*)&pW1[((ks * 8 + ct) * 64 + l) * 8];
      acc = __builtin_amdgcn_mfma_f32_16x16x32_bf16(dfrag[ks], b, acc, 0, 0, 0);
    }
    const int ksp = ct >> 1, gp = ((ct & 1) * 16 + col16) >> 3, jp = col16 & 7;
#pragma unroll
    for (int j = 0; j < 4; j++)
      ph1[((rt * 4 + ksp) * 64 + gp * 16 + rr + j) * 8 + jp] = f2bf(fmaxf(acc[j], 0.0f));
  }
  __syncthreads();
  // L2: K=128, N=128
  for (int ci = 0; ci < 4; ci++) {
    const int ct = ch * 4 + ci;
    const int col = ct * 16 + col16;
    f32x4 acc = bc4(b2[col]);
#pragma unroll
    for (int ks = 0; ks < 4; ks++) {
      bf16x8 a = *(const bf16x8*)&ph1[((rt * 4 + ks) * 64 + l) * 8];
      bf16x8 b = *(const bf16x8*)&pW2[((ks * 8 + ct) * 64 + l) * 8];
      acc = __builtin_amdgcn_mfma_f32_16x16x32_bf16(a, b, acc, 0, 0, 0);
    }
    const int ksp = ct >> 1, gp = ((ct & 1) * 16 + col16) >> 3, jp = col16 & 7;
#pragma unroll
    for (int j = 0; j < 4; j++)
      ph2[((rt * 4 + ksp) * 64 + gp * 16 + rr + j) * 8 + jp] = f2bf(fmaxf(acc[j], 0.0f));
  }
  __syncthreads();
  // L3: K=128, N=32 (cols >= 20 zero-padded in pW3); this wave: ct = ch
  const int col = ch * 16 + col16;
  f32x4 acc = bc4((col < KMIX) ? b3[col] : 0.0f);
#pragma unroll
  for (int ks = 0; ks < 4; ks++) {
    bf16x8 a = *(const bf16x8*)&ph2[((rt * 4 + ks) * 64 + l) * 8];
    bf16x8 b = *(const bf16x8*)&pW3[((ks * 2 + ch) * 64 + l) * 8];
    acc = __builtin_amdgcn_mfma_f32_16x16x32_bf16(a, b, acc, 0, 0, 0);
  }
  return acc;
}

__global__ __launch_bounds__(512, 4) void k_head_mfma(
    const unsigned short* __restrict__ stbf, const int* __restrict__ nig,
    const float* __restrict__ label, const int* __restrict__ subidx,
    const short* __restrict__ pWt1, const float* __restrict__ bt1,
    const short* __restrict__ pWt2, const float* __restrict__ bt2,
    const short* __restrict__ pWt3, const float* __restrict__ bt3,
    const short* __restrict__ pWa1, const float* __restrict__ ba1,
    const short* __restrict__ pWa2, const float* __restrict__ ba2,
    const short* __restrict__ pWa3, const float* __restrict__ ba3,
    float* __restrict__ red_loss, float* __restrict__ red_alpha,
    float* __restrict__ cnt) {
  __shared__ short ph1[8192];   // [rt<4][ks<4][64][8]
  __shared__ short ph2[8192];
  __shared__ float la[64 * KMIX];
  __shared__ int   ssub[64];
  __shared__ float slab[64];
  __shared__ float lse[64];

  const int t = threadIdx.x;
  const int r0 = blockIdx.x * 64;

  if (t < 64) {
    const int gr = r0 + t;
    const int sb = (gr < NEOUT) ? subidx[gr] : 0;
    ssub[t] = sb;
    slab[t] = (gr < NEOUT) ? label[gr] : 0.0f;
    if (gr < NEOUT) atomicAdd(&cnt[sb], 1.0f);
  }

  const int wid = t >> 6, l = t & 63;
  const int rt = wid & 3, ch = wid >> 2;
  const int col16 = l & 15, rr = (l >> 4) * 4;
  const int cb = (l >> 4) * 8;

  // diff A-frags in registers: row rt*16+(l&15)
  bf16x8 dfrag[6];
  {
    const int gr = r0 + rt * 16 + (l & 15);
    const int ok = (gr < NEOUT);
    const int ia = ok ? nig[2 * gr] : 0;
    const int ib = ok ? nig[2 * gr + 1] : 0;   // ia==ib -> zero diff for pad rows
    const unsigned short* pa = &stbf[(size_t)ia * DDIM + cb];
    const unsigned short* pb = &stbf[(size_t)ib * DDIM + cb];
#pragma unroll
    for (int ks = 0; ks < 6; ks++) {
      const u16x8 a = *(const u16x8*)(pa + ks * 32);
      const u16x8 b = *(const u16x8*)(pb + ks * 32);
      short v[8];
#pragma unroll
      for (int j = 0; j < 8; j++) v[j] = f2bf(bf2f(a[j]) - bf2f(b[j]));
      dfrag[ks] = *(bf16x8*)v;
    }
  }
  __syncthreads();   // also covers ssub/slab visibility

  // ---- theta ----
  {
    const f32x4 o = head_branch(dfrag, ph1, ph2, pWt1, bt1, pWt2, bt2, pWt3, bt3, rt, ch, l);
    const int col = ch * 16 + col16;
    if (col < KMIX) {
#pragma unroll
      for (int j = 0; j < 4; j++) {
        const int r = rt * 16 + rr + j;
        if (r0 + r < NEOUT) {
          const float lt = o[j];
          const float adj = fmaxf(lt, 0.0f) + logf(1.0f + __expf(-fabsf(lt))) - lt * slab[r];
          atomicAdd(&red_loss[ssub[r] * KMIX + col], adj);
        }
      }
    }
  }
  __syncthreads();   // theta L3 ph2 reads done before alpha overwrites
  // ---- alpha ----
  {
    const f32x4 o = head_branch(dfrag, ph1, ph2, pWa1, ba1, pWa2, ba2, pWa3, ba3, rt, ch, l);
    const int col = ch * 16 + col16;
    if (col < KMIX) {
#pragma unroll
      for (int j = 0; j < 4; j++) {
        const int r = rt * 16 + rr + j;
        la[r * KMIX + col] = o[j];
      }
    }
  }
  __syncthreads();
  if (t < 64) {
    float m = -1e30f;
    for (int k = 0; k < KMIX; k++) m = fmaxf(m, la[t * KMIX + k]);
    float s = 0.0f;
    for (int k = 0; k < KMIX; k++) s += __expf(la[t * KMIX + k] - m);
    lse[t] = m + logf(s);
  }
  __syncthreads();
  {
    const int r = t >> 3;
    if (r0 + r < NEOUT) {
#pragma unroll
      for (int i = 0; i < 3; i++) {
        const int c = (t & 7) + 8 * i;
        if (c < KMIX)
          atomicAdd(&red_alpha[ssub[r] * KMIX + c], la[r * KMIX + c] - lse[r]);
      }
    }
  }
}

// ---------------- final: per-subgraph logsumexp, reduce to scalar
__global__ __launch_bounds__(1024) void k_final(
    const float* __restrict__ red_loss, const float* __restrict__ red_alpha,
    const float* __restrict__ cnt, float* __restrict__ out) {
  __shared__ float part[1024];
  const int s = threadIdx.x;
  const float c = fmaxf(cnt[s], 1.0f);
  float v[KMIX];
  float m = -1e30f;
  for (int k = 0; k < KMIX; k++) {
    v[k] = -red_loss[s * KMIX + k] + red_alpha[s * KMIX + k] / c;
    m = fmaxf(m, v[k]);
  }
  float sum = 0.0f;
  for (int k = 0; k < KMIX; k++) sum += __expf(v[k] - m);
  part[s] = m + logf(sum);
  __syncthreads();
  for (int st = 512; st > 0; st >>= 1) {
    if (s < st) part[s] += part[s + st];
    __syncthreads();
  }
  if (s == 0) out[0] = -part[0] / (float)NEOUT;
}

extern "C" void kernel_launch(void* const* d_in, const int* in_sizes, int n_in,
                              void* d_out, int out_size, void* d_ws, size_t ws_size,
                              hipStream_t stream) {
  const float* A      = (const float*)d_in[0];
  const int*   edges  = (const int*)d_in[1];
  const int*   attidx = (const int*)d_in[2];
  const int*   nif    = (const int*)d_in[3];
  const int*   cl     = (const int*)d_in[4];
  const int*   nig    = (const int*)d_in[5];
  const float* label  = (const float*)d_in[6];
  const int*   subidx = (const int*)d_in[7];
  const float* Wdec   = (const float*)d_in[8];
  const float* bdec   = (const float*)d_in[9];
  const float* cemb   = (const float*)d_in[10];
  const float* Wm1    = (const float*)d_in[11];
  const float* bm1    = (const float*)d_in[12];
  const float* Wm2    = (const float*)d_in[13];
  const float* bm2    = (const float*)d_in[14];
  const float* Wa1    = (const float*)d_in[15];
  const float* ba1    = (const float*)d_in[16];
  const float* Wa2    = (const float*)d_in[17];
  const float* ba2    = (const float*)d_in[18];
  const float* Wih    = (const float*)d_in[19];
  const float* bih    = (const float*)d_in[20];
  const float* Whh    = (const float*)d_in[21];
  const float* bhh    = (const float*)d_in[22];
  const float* Wt1    = (const float*)d_in[23];
  const float* bt1    = (const float*)d_in[24];
  const float* Wt2    = (const float*)d_in[25];
  const float* bt2    = (const float*)d_in[26];
  const float* Wt3    = (const float*)d_in[27];
  const float* bt3    = (const float*)d_in[28];
  const float* Wha1   = (const float*)d_in[29];
  const float* hba1   = (const float*)d_in[30];
  const float* Wha2   = (const float*)d_in[31];
  const float* hba2   = (const float*)d_in[32];
  const float* Wha3   = (const float*)d_in[33];
  const float* hba3   = (const float*)d_in[34];

  char* ws = (char*)d_ws;
  const size_t SZ_STBF = (size_t)NGNN * DDIM * sizeof(short);    // 12.6 MB
  const size_t SZ_AGG  = (size_t)NGNN * DDIM * sizeof(float);    // 25.2 MB
  unsigned short* stbf = (unsigned short*)ws;
  float* agg       = (float*)(ws + SZ_STBF);
  float* nf        = agg;  // decode output overlays agg (dead before first memset)
  float* red_loss  = (float*)(ws + SZ_STBF + SZ_AGG);
  float* red_alpha = red_loss + NSUB * KMIX;
  float* cnt       = red_alpha + NSUB * KMIX;
  short* pk        = (short*)(ws + SZ_STBF + SZ_AGG +
                              (((size_t)(2 * NSUB * KMIX + NSUB) * 4 + 255) / 256) * 256);
  short* pWm1  = pk;             // 6*12*512
  short* pWa1e = pWm1  + 36864;  // 6*8*512
  short* pWm2  = pWa1e + 24576;  // 6*12*512
  short* pWa2e = pWm2  + 36864;  // 4*12*512
  short* pWt1  = pWa2e + 24576;  // 6*8*512
  short* pWt2  = pWt1  + 24576;  // 4*8*512
  short* pWt3  = pWt2  + 16384;  // 4*2*512
  short* pWh1  = pWt3  + 4096;   // 6*8*512
  short* pWh2  = pWh1  + 24576;  // 4*8*512
  short* pWh3  = pWh2  + 16384;  // 4*2*512
  short* pWih  = pWh3  + 4096;   // 6*36*512
  short* pWhh  = pWih  + 110592; // 6*36*512

  // pack weights to bf16 B-fragment layout (grid = (K/32)*CT)
  k_pack<<<72, 64, 0, stream>>>(Wm1,  pWm1,  192, 12);
  k_pack<<<48, 64, 0, stream>>>(Wa1,  pWa1e, 128, 8);
  k_pack<<<72, 64, 0, stream>>>(Wm2,  pWm2,  192, 12);
  k_pack<<<48, 64, 0, stream>>>(Wa2,  pWa2e, 192, 12);
  k_pack<<<48, 64, 0, stream>>>(Wt1,  pWt1,  128, 8);
  k_pack<<<32, 64, 0, stream>>>(Wt2,  pWt2,  128, 8);
  k_pack<<< 8, 64, 0, stream>>>(Wt3,  pWt3,   20, 2);
  k_pack<<<48, 64, 0, stream>>>(Wha1, pWh1,  128, 8);
  k_pack<<<32, 64, 0, stream>>>(Wha2, pWh2,  128, 8);
  k_pack<<< 8, 64, 0, stream>>>(Wha3, pWh3,   20, 2);
  k_pack<<<216, 64, 0, stream>>>(Wih, pWih,  576, 36);
  k_pack<<<216, 64, 0, stream>>>(Whh, pWhh,  576, 36);

  k_dec<<<NGNN, 128, 0, stream>>>(A, Wdec, bdec, nf);
  k_state<<<NGNN, 192, 0, stream>>>(nf, cemb, nif, cl, stbf);
  for (int p = 0; p < 2; p++) {
    hipMemsetAsync(agg, 0, SZ_AGG, stream);
    k_edge_mfma<<<NEDGE / 32, 128, 0, stream>>>(stbf, edges, attidx,
        Wm1, bm1, pWm1, pWm2, bm2, Wa1, ba1, pWa1e, pWa2e, ba2, agg);
    k_gru_mfma<<<NGNN / 64, 256, 0, stream>>>(stbf, agg, pWih, bih, pWhh, bhh);
  }
  hipMemsetAsync(red_loss, 0, (size_t)(2 * NSUB * KMIX + NSUB) * sizeof(float), stream);
  k_head_mfma<<<(NEOUT + 63) / 64, 512, 0, stream>>>(stbf, nig, label, subidx,
      pWt1, bt1, pWt2, bt2, pWt3, bt3, pWh1, hba1, pWh2, hba2, pWh3, hba3,
      red_loss, red_alpha, cnt);
  k_final<<<1, 1024, 0, stream>>>(red_loss, red_alpha, cnt, (float*)d_out);
}

// Round 5
// 962.697 us; speedup vs baseline: 4.1401x; 1.0249x over previous
//
#include <hip/hip_runtime.h>
#include <math.h>

#define NGNN   32768
#define NMAXD  1024
#define HIDD   128
#define CLSD   64
#define DDIM   192
#define ATTH   128
#define NEDGE  200000
#define NEOUT  500000
#define NSUB   1024
#define KMIX   20

#define NREP      64
#define LOSS_OFF  0
#define ALPHA_OFF 20480
#define CNT_OFF   40960
#define REP_STRIDE 41984

typedef __attribute__((ext_vector_type(8))) short bf16x8;
typedef __attribute__((ext_vector_type(8))) unsigned short u16x8;
typedef __attribute__((ext_vector_type(4))) float f32x4;

__device__ __forceinline__ float sigm(float x) { return 1.0f / (1.0f + __expf(-x)); }
__device__ __forceinline__ float tanhf_(float x) { return 2.0f / (1.0f + __expf(-2.0f * x)) - 1.0f; }

__device__ __forceinline__ short f2bf(float f) {
  union { float f; unsigned u; } v; v.f = f;
  unsigned r = v.u + 0x7FFFu + ((v.u >> 16) & 1u);
  return (short)(r >> 16);
}
__device__ __forceinline__ float bf2f(unsigned short u) {
  union { unsigned u; float f; } v; v.u = ((unsigned)u) << 16;
  return v.f;
}
__device__ __forceinline__ f32x4 bc4(float b) {
  f32x4 v; v[0] = b; v[1] = b; v[2] = b; v[3] = b; return v;
}

// ---------------- pack fp32 [K][N] weight into bf16 MFMA B-fragment order
__global__ __launch_bounds__(64) void k_pack(const float* __restrict__ W,
                                             short* __restrict__ out, int N, int CT) {
  const int l = threadIdx.x;
  const int ks = blockIdx.x / CT;
  const int ct = blockIdx.x % CT;
  const int row0 = ks * 32 + (l >> 4) * 8;
  const int col = ct * 16 + (l & 15);
  short v[8];
#pragma unroll
  for (int j = 0; j < 8; j++) {
    const float f = (col < N) ? W[(size_t)(row0 + j) * N + col] : 0.0f;
    v[j] = f2bf(f);
  }
  *(bf16x8*)(out + ((size_t)blockIdx.x * 64 + l) * 8) = *(bf16x8*)v;
}

// ---------------- nf = A @ W_dec + b_dec, exploiting A in {0,1} with ~5% density
__global__ __launch_bounds__(128) void k_dec(
    const float* __restrict__ A, const float* __restrict__ Wd,
    const float* __restrict__ bd, float* __restrict__ nf) {
  __shared__ float arow[NMAXD];
  __shared__ int   nz[NMAXD];
  __shared__ int   cnt;
  const int row = blockIdx.x;
  const int t = threadIdx.x;
  if (t == 0) cnt = 0;
  const float4* A4 = (const float4*)(A + (size_t)row * NMAXD);
  float4* a4 = (float4*)arow;
  a4[t] = A4[t];
  a4[t + 128] = A4[t + 128];
  __syncthreads();
  for (int i = t; i < NMAXD; i += 128) {
    if (arow[i] != 0.0f) {
      int p = atomicAdd(&cnt, 1);
      nz[p] = i;
    }
  }
  __syncthreads();
  float acc = bd[t];
  const int n = cnt;
  for (int i = 0; i < n; i++) acc += Wd[(size_t)nz[i] * HIDD + t];
  nf[(size_t)row * HIDD + t] = acc;
}

// ---------------- stbf[i] = bf16(concat(nf[nif[i]] (0-row aware), class_emb[cl[i]]))
__global__ __launch_bounds__(192) void k_state(
    const float* __restrict__ nf, const float* __restrict__ cemb,
    const int* __restrict__ nif, const int* __restrict__ cl,
    unsigned short* __restrict__ stbf) {
  const int i = blockIdx.x;
  const int t = threadIdx.x;
  float v;
  if (t < HIDD) {
    const int idx = nif[i];
    v = (idx == 0) ? 0.0f : nf[(size_t)(idx - 1) * HIDD + t];
  } else {
    v = cemb[cl[i] * CLSD + (t - HIDD)];
  }
  stbf[(size_t)i * DDIM + t] = (unsigned short)f2bf(v);
}

// ---------------- MFMA edge kernel: 32 edges/block, 128 threads (2 waves)
__global__ __launch_bounds__(128, 4) void k_edge_mfma(
    const unsigned short* __restrict__ stbf, const int* __restrict__ edges,
    const int* __restrict__ attidx,
    const float* __restrict__ Wm1, const float* __restrict__ bm1,
    const short* __restrict__ pWm1, const short* __restrict__ pWm2,
    const float* __restrict__ bm2,
    const float* __restrict__ Wa1, const float* __restrict__ ba1,
    const short* __restrict__ pWa1, const short* __restrict__ pWa2,
    const float* __restrict__ ba2,
    float* __restrict__ agg) {
  __shared__ short phm[6144];    // hm A-frags (K=192) [wid<2][ks<6][64][8]
  __shared__ short pha[4096];    // ha A-frags (K=128) [wid<2][ks<4][64][8]
  const int t = threadIdx.x;
  const int e0 = blockIdx.x * 32;
  const int wid = t >> 6, l = t & 63;
  const int col16 = l & 15, rr = (l >> 4) * 4;
  const int cb = (l >> 4) * 8;

  // diff A-frags: lane l holds row wid*16+(l&15), k-cols ks*32+cb..+8
  bf16x8 dfrag[6];
  {
    const int e = e0 + wid * 16 + (l & 15);
    const int s = edges[2 * e], d = edges[2 * e + 1];
    const unsigned short* ps = &stbf[(size_t)s * DDIM + cb];
    const unsigned short* pd_ = &stbf[(size_t)d * DDIM + cb];
#pragma unroll
    for (int ks = 0; ks < 6; ks++) {
      const u16x8 a = *(const u16x8*)(ps + ks * 32);
      const u16x8 b = *(const u16x8*)(pd_ + ks * 32);
      short v[8];
#pragma unroll
      for (int j = 0; j < 8; j++) v[j] = f2bf(bf2f(a[j]) - bf2f(b[j]));
      dfrag[ks] = *(bf16x8*)v;
    }
  }
  // per-lane metadata for its 4 output rows
  int a0r[4], a1r[4], dstr[4];
#pragma unroll
  for (int j = 0; j < 4; j++) {
    const int e = e0 + wid * 16 + rr + j;
    const int s = edges[2 * e], d = edges[2 * e + 1];
    a0r[j] = attidx[s]; a1r[j] = attidx[d]; dstr[j] = d;
  }

  // msg L1: [32x192]@[192x192], one-hot part via fp32 gathers into acc init
  for (int ct = 0; ct < 12; ct++) {
    const int col = ct * 16 + col16;
    f32x4 acc;
#pragma unroll
    for (int j = 0; j < 4; j++)
      acc[j] = bm1[col] + Wm1[(size_t)(DDIM + a0r[j]) * DDIM + col]
                        + Wm1[(size_t)(DDIM + 64 + a1r[j]) * DDIM + col];
#pragma unroll
    for (int ks = 0; ks < 6; ks++) {
      bf16x8 b = *(const bf16x8*)&pWm1[((ks * 12 + ct) * 64 + l) * 8];
      acc = __builtin_amdgcn_mfma_f32_16x16x32_bf16(dfrag[ks], b, acc, 0, 0, 0);
    }
    const int ksp = col >> 5, gp = (col & 31) >> 3, jp = col & 7;
#pragma unroll
    for (int j = 0; j < 4; j++)
      phm[((wid * 6 + ksp) * 64 + gp * 16 + rr + j) * 8 + jp] = f2bf(fmaxf(acc[j], 0.0f));
  }
  // att L1: [32x192]@[192x128]
  for (int ct = 0; ct < 8; ct++) {
    const int col = ct * 16 + col16;
    f32x4 acc;
#pragma unroll
    for (int j = 0; j < 4; j++)
      acc[j] = ba1[col] + Wa1[(size_t)(DDIM + a0r[j]) * ATTH + col]
                        + Wa1[(size_t)(DDIM + 64 + a1r[j]) * ATTH + col];
#pragma unroll
    for (int ks = 0; ks < 6; ks++) {
      bf16x8 b = *(const bf16x8*)&pWa1[((ks * 8 + ct) * 64 + l) * 8];
      acc = __builtin_amdgcn_mfma_f32_16x16x32_bf16(dfrag[ks], b, acc, 0, 0, 0);
    }
    const int ksp = ct >> 1, gp = ((ct & 1) * 16 + col16) >> 3, jp = col16 & 7;
#pragma unroll
    for (int j = 0; j < 4; j++)
      pha[((wid * 4 + ksp) * 64 + gp * 16 + rr + j) * 8 + jp] = f2bf(fmaxf(acc[j], 0.0f));
  }
  __syncthreads();

  // L2 (msg: K=192, att: K=128, both N=192), combine msg*sigm(att), scatter-add
  for (int ct = 0; ct < 12; ct++) {
    const int col = ct * 16 + col16;
    f32x4 m = bc4(bm2[col]), av = bc4(ba2[col]);
#pragma unroll
    for (int ks = 0; ks < 6; ks++) {
      bf16x8 a = *(const bf16x8*)&phm[((wid * 6 + ks) * 64 + l) * 8];
      bf16x8 b = *(const bf16x8*)&pWm2[((ks * 12 + ct) * 64 + l) * 8];
      m = __builtin_amdgcn_mfma_f32_16x16x32_bf16(a, b, m, 0, 0, 0);
    }
#pragma unroll
    for (int ks = 0; ks < 4; ks++) {
      bf16x8 a = *(const bf16x8*)&pha[((wid * 4 + ks) * 64 + l) * 8];
      bf16x8 b = *(const bf16x8*)&pWa2[((ks * 12 + ct) * 64 + l) * 8];
      av = __builtin_amdgcn_mfma_f32_16x16x32_bf16(a, b, av, 0, 0, 0);
    }
#pragma unroll
    for (int j = 0; j < 4; j++) {
      atomicAdd(&agg[(size_t)dstr[j] * DDIM + col], m[j] * sigm(av[j]));
    }
  }
}

// ---------------- MFMA GRU: 64 nodes/block, 256 threads (4 waves), zero LDS.
__global__ __launch_bounds__(256, 2) void k_gru_mfma(
    unsigned short* __restrict__ stbf, const float* __restrict__ agg,
    const short* __restrict__ pWih, const float* __restrict__ bih,
    const short* __restrict__ pWhh, const float* __restrict__ bhh) {
  const int t = threadIdx.x;
  const int n0 = blockIdx.x * 64;
  const int wid = t >> 6, l = t & 63;
  const int col16 = l & 15, rr = (l >> 4) * 4;
  const int cb = (l >> 4) * 8;
  const int row = n0 + wid * 16 + (l & 15);

  bf16x8 af[6], sf[6];
#pragma unroll
  for (int ks = 0; ks < 6; ks++) {
    const float4 a0 = *(const float4*)&agg[(size_t)row * DDIM + ks * 32 + cb];
    const float4 a1 = *(const float4*)&agg[(size_t)row * DDIM + ks * 32 + cb + 4];
    short v[8];
    v[0] = f2bf(a0.x); v[1] = f2bf(a0.y); v[2] = f2bf(a0.z); v[3] = f2bf(a0.w);
    v[4] = f2bf(a1.x); v[5] = f2bf(a1.y); v[6] = f2bf(a1.z); v[7] = f2bf(a1.w);
    af[ks] = *(bf16x8*)v;
    sf[ks] = *(const bf16x8*)&stbf[(size_t)row * DDIM + ks * 32 + cb];
  }

  for (int ct = 0; ct < 12; ct++) {
    const int c = ct * 16 + col16;
    f32x4 ir = bc4(bih[c]), iz = bc4(bih[c + DDIM]), in_ = bc4(bih[c + 2 * DDIM]);
    f32x4 hr = bc4(bhh[c]), hz = bc4(bhh[c + DDIM]), hn = bc4(bhh[c + 2 * DDIM]);
#pragma unroll
    for (int ks = 0; ks < 6; ks++) {
      const bf16x8 wr = *(const bf16x8*)&pWih[((size_t)(ks * 36 + ct) * 64 + l) * 8];
      const bf16x8 wz = *(const bf16x8*)&pWih[((size_t)(ks * 36 + ct + 12) * 64 + l) * 8];
      const bf16x8 wn = *(const bf16x8*)&pWih[((size_t)(ks * 36 + ct + 24) * 64 + l) * 8];
      ir  = __builtin_amdgcn_mfma_f32_16x16x32_bf16(af[ks], wr, ir, 0, 0, 0);
      iz  = __builtin_amdgcn_mfma_f32_16x16x32_bf16(af[ks], wz, iz, 0, 0, 0);
      in_ = __builtin_amdgcn_mfma_f32_16x16x32_bf16(af[ks], wn, in_, 0, 0, 0);
      const bf16x8 vr = *(const bf16x8*)&pWhh[((size_t)(ks * 36 + ct) * 64 + l) * 8];
      const bf16x8 vz = *(const bf16x8*)&pWhh[((size_t)(ks * 36 + ct + 12) * 64 + l) * 8];
      const bf16x8 vn = *(const bf16x8*)&pWhh[((size_t)(ks * 36 + ct + 24) * 64 + l) * 8];
      hr = __builtin_amdgcn_mfma_f32_16x16x32_bf16(sf[ks], vr, hr, 0, 0, 0);
      hz = __builtin_amdgcn_mfma_f32_16x16x32_bf16(sf[ks], vz, hz, 0, 0, 0);
      hn = __builtin_amdgcn_mfma_f32_16x16x32_bf16(sf[ks], vn, hn, 0, 0, 0);
    }
#pragma unroll
    for (int j = 0; j < 4; j++) {
      const size_t idx = (size_t)(n0 + wid * 16 + rr + j) * DDIM + c;
      const float sv = bf2f(stbf[idx]);
      const float r = sigm(ir[j] + hr[j]);
      const float z = sigm(iz[j] + hz[j]);
      const float nn = tanhf_(in_[j] + r * hn[j]);
      stbf[idx] = (unsigned short)f2bf((1.0f - z) * nn + z * sv);
    }
  }
}

// ---------------- MFMA head: 64 rows/block, 512 threads (8 waves), theta+alpha FUSED.
// rt = wid&3 row tile (16 rows), ch = wid>>2 column half.
__global__ __launch_bounds__(512, 2) void k_head_mfma(
    const unsigned short* __restrict__ stbf, const int* __restrict__ nig,
    const float* __restrict__ label, const int* __restrict__ subidx,
    const short* __restrict__ pWt1, const float* __restrict__ bt1,
    const short* __restrict__ pWt2, const float* __restrict__ bt2,
    const short* __restrict__ pWt3, const float* __restrict__ bt3,
    const short* __restrict__ pWa1, const float* __restrict__ ba1,
    const short* __restrict__ pWa2, const float* __restrict__ ba2,
    const short* __restrict__ pWa3, const float* __restrict__ ba3,
    float* __restrict__ REP) {
  __shared__ short ph1t[8192], ph1a[8192];   // [rt<4][ks<4][64][8]
  __shared__ short ph2t[8192], ph2a[8192];
  __shared__ float la[64 * KMIX];
  __shared__ int   ssub[64];
  __shared__ float slab[64];
  __shared__ float lse[64];

  const int t = threadIdx.x;
  const int r0 = blockIdx.x * 64;
  float* rep = REP + (size_t)(blockIdx.x & (NREP - 1)) * REP_STRIDE;

  if (t < 64) {
    const int gr = r0 + t;
    const int sb = (gr < NEOUT) ? subidx[gr] : 0;
    ssub[t] = sb;
    slab[t] = (gr < NEOUT) ? label[gr] : 0.0f;
    if (gr < NEOUT) atomicAdd(&rep[CNT_OFF + sb], 1.0f);
  }

  const int wid = t >> 6, l = t & 63;
  const int rt = wid & 3, ch = wid >> 2;
  const int col16 = l & 15, rr = (l >> 4) * 4;
  const int cb = (l >> 4) * 8;

  // diff A-frags in registers: row rt*16+(l&15)
  bf16x8 dfrag[6];
  {
    const int gr = r0 + rt * 16 + (l & 15);
    const int ok = (gr < NEOUT);
    const int ia = ok ? nig[2 * gr] : 0;
    const int ib = ok ? nig[2 * gr + 1] : 0;
    const unsigned short* pa = &stbf[(size_t)ia * DDIM + cb];
    const unsigned short* pb = &stbf[(size_t)ib * DDIM + cb];
#pragma unroll
    for (int ks = 0; ks < 6; ks++) {
      const u16x8 a = *(const u16x8*)(pa + ks * 32);
      const u16x8 b = *(const u16x8*)(pb + ks * 32);
      short v[8];
#pragma unroll
      for (int j = 0; j < 8; j++) v[j] = f2bf(bf2f(a[j]) - bf2f(b[j]));
      dfrag[ks] = *(bf16x8*)v;
    }
  }

  // L1 fused: K=192, N=128; this wave does cols [ch*64, ch*64+64)
  for (int ci = 0; ci < 4; ci++) {
    const int ct = ch * 4 + ci;
    const int col = ct * 16 + col16;
    f32x4 at = bc4(bt1[col]), aa = bc4(ba1[col]);
#pragma unroll
    for (int ks = 0; ks < 6; ks++) {
      bf16x8 b1 = *(const bf16x8*)&pWt1[((ks * 8 + ct) * 64 + l) * 8];
      bf16x8 b2 = *(const bf16x8*)&pWa1[((ks * 8 + ct) * 64 + l) * 8];
      at = __builtin_amdgcn_mfma_f32_16x16x32_bf16(dfrag[ks], b1, at, 0, 0, 0);
      aa = __builtin_amdgcn_mfma_f32_16x16x32_bf16(dfrag[ks], b2, aa, 0, 0, 0);
    }
    const int ksp = ct >> 1, gp = ((ct & 1) * 16 + col16) >> 3, jp = col16 & 7;
#pragma unroll
    for (int j = 0; j < 4; j++) {
      const int o = ((rt * 4 + ksp) * 64 + gp * 16 + rr + j) * 8 + jp;
      ph1t[o] = f2bf(fmaxf(at[j], 0.0f));
      ph1a[o] = f2bf(fmaxf(aa[j], 0.0f));
    }
  }
  __syncthreads();
  // L2 fused: K=128, N=128
  for (int ci = 0; ci < 4; ci++) {
    const int ct = ch * 4 + ci;
    const int col = ct * 16 + col16;
    f32x4 at = bc4(bt2[col]), aa = bc4(ba2[col]);
#pragma unroll
    for (int ks = 0; ks < 4; ks++) {
      const int ao = ((rt * 4 + ks) * 64 + l) * 8;
      bf16x8 a1 = *(const bf16x8*)&ph1t[ao];
      bf16x8 a2 = *(const bf16x8*)&ph1a[ao];
      bf16x8 b1 = *(const bf16x8*)&pWt2[((ks * 8 + ct) * 64 + l) * 8];
      bf16x8 b2 = *(const bf16x8*)&pWa2[((ks * 8 + ct) * 64 + l) * 8];
      at = __builtin_amdgcn_mfma_f32_16x16x32_bf16(a1, b1, at, 0, 0, 0);
      aa = __builtin_amdgcn_mfma_f32_16x16x32_bf16(a2, b2, aa, 0, 0, 0);
    }
    const int ksp = ct >> 1, gp = ((ct & 1) * 16 + col16) >> 3, jp = col16 & 7;
#pragma unroll
    for (int j = 0; j < 4; j++) {
      const int o = ((rt * 4 + ksp) * 64 + gp * 16 + rr + j) * 8 + jp;
      ph2t[o] = f2bf(fmaxf(at[j], 0.0f));
      ph2a[o] = f2bf(fmaxf(aa[j], 0.0f));
    }
  }
  __syncthreads();
  // L3 fused: K=128, N=32 (cols >= 20 zero-padded); this wave: ct = ch
  const int col = ch * 16 + col16;
  f32x4 ot = bc4((col < KMIX) ? bt3[col] : 0.0f);
  f32x4 oa = bc4((col < KMIX) ? ba3[col] : 0.0f);
#pragma unroll
  for (int ks = 0; ks < 4; ks++) {
    const int ao = ((rt * 4 + ks) * 64 + l) * 8;
    bf16x8 a1 = *(const bf16x8*)&ph2t[ao];
    bf16x8 a2 = *(const bf16x8*)&ph2a[ao];
    bf16x8 b1 = *(const bf16x8*)&pWt3[((ks * 2 + ch) * 64 + l) * 8];
    bf16x8 b2 = *(const bf16x8*)&pWa3[((ks * 2 + ch) * 64 + l) * 8];
    ot = __builtin_amdgcn_mfma_f32_16x16x32_bf16(a1, b1, ot, 0, 0, 0);
    oa = __builtin_amdgcn_mfma_f32_16x16x32_bf16(a2, b2, oa, 0, 0, 0);
  }

  // epilogue: theta -> replica atomics; alpha -> la, lse, replica atomics
  if (col < KMIX) {
#pragma unroll
    for (int j = 0; j < 4; j++) {
      const int r = rt * 16 + rr + j;
      if (r0 + r < NEOUT) {
        const float lt = ot[j];
        const float adj = fmaxf(lt, 0.0f) + logf(1.0f + __expf(-fabsf(lt))) - lt * slab[r];
        atomicAdd(&rep[LOSS_OFF + ssub[r] * KMIX + col], adj);
      }
      la[(rt * 16 + rr + j) * KMIX + col] = oa[j];
    }
  }
  __syncthreads();
  if (t < 64) {
    float m = -1e30f;
    for (int k = 0; k < KMIX; k++) m = fmaxf(m, la[t * KMIX + k]);
    float s = 0.0f;
    for (int k = 0; k < KMIX; k++) s += __expf(la[t * KMIX + k] - m);
    lse[t] = m + logf(s);
  }
  __syncthreads();
  {
    const int r = t >> 3;
    if (r0 + r < NEOUT) {
#pragma unroll
      for (int i = 0; i < 3; i++) {
        const int c = (t & 7) + 8 * i;
        if (c < KMIX)
          atomicAdd(&rep[ALPHA_OFF + ssub[r] * KMIX + c], la[r * KMIX + c] - lse[r]);
      }
    }
  }
}

// ---------------- fold 64 replicas into final arrays (coalesced)
__global__ __launch_bounds__(256) void k_red(const float* __restrict__ REP,
                                             float* __restrict__ fin) {
  const int i = blockIdx.x * 256 + threadIdx.x;
  if (i < REP_STRIDE) {
    float s = 0.0f;
    for (int r = 0; r < NREP; r++) s += REP[(size_t)r * REP_STRIDE + i];
    fin[i] = s;
  }
}

// ---------------- final: per-subgraph logsumexp, reduce to scalar
__global__ __launch_bounds__(1024) void k_final(
    const float* __restrict__ fin, float* __restrict__ out) {
  __shared__ float part[1024];
  const int s = threadIdx.x;
  const float* red_loss  = fin + LOSS_OFF;
  const float* red_alpha = fin + ALPHA_OFF;
  const float c = fmaxf(fin[CNT_OFF + s], 1.0f);
  float v[KMIX];
  float m = -1e30f;
  for (int k = 0; k < KMIX; k++) {
    v[k] = -red_loss[s * KMIX + k] + red_alpha[s * KMIX + k] / c;
    m = fmaxf(m, v[k]);
  }
  float sum = 0.0f;
  for (int k = 0; k < KMIX; k++) sum += __expf(v[k] - m);
  part[s] = m + logf(sum);
  __syncthreads();
  for (int st = 512; st > 0; st >>= 1) {
    if (s < st) part[s] += part[s + st];
    __syncthreads();
  }
  if (s == 0) out[0] = -part[0] / (float)NEOUT;
}

extern "C" void kernel_launch(void* const* d_in, const int* in_sizes, int n_in,
                              void* d_out, int out_size, void* d_ws, size_t ws_size,
                              hipStream_t stream) {
  const float* A      = (const float*)d_in[0];
  const int*   edges  = (const int*)d_in[1];
  const int*   attidx = (const int*)d_in[2];
  const int*   nif    = (const int*)d_in[3];
  const int*   cl     = (const int*)d_in[4];
  const int*   nig    = (const int*)d_in[5];
  const float* label  = (const float*)d_in[6];
  const int*   subidx = (const int*)d_in[7];
  const float* Wdec   = (const float*)d_in[8];
  const float* bdec   = (const float*)d_in[9];
  const float* cemb   = (const float*)d_in[10];
  const float* Wm1    = (const float*)d_in[11];
  const float* bm1    = (const float*)d_in[12];
  const float* Wm2    = (const float*)d_in[13];
  const float* bm2    = (const float*)d_in[14];
  const float* Wa1    = (const float*)d_in[15];
  const float* ba1    = (const float*)d_in[16];
  const float* Wa2    = (const float*)d_in[17];
  const float* ba2    = (const float*)d_in[18];
  const float* Wih    = (const float*)d_in[19];
  const float* bih    = (const float*)d_in[20];
  const float* Whh    = (const float*)d_in[21];
  const float* bhh    = (const float*)d_in[22];
  const float* Wt1    = (const float*)d_in[23];
  const float* bt1    = (const float*)d_in[24];
  const float* Wt2    = (const float*)d_in[25];
  const float* bt2    = (const float*)d_in[26];
  const float* Wt3    = (const float*)d_in[27];
  const float* bt3    = (const float*)d_in[28];
  const float* Wha1   = (const float*)d_in[29];
  const float* hba1   = (const float*)d_in[30];
  const float* Wha2   = (const float*)d_in[31];
  const float* hba2   = (const float*)d_in[32];
  const float* Wha3   = (const float*)d_in[33];
  const float* hba3   = (const float*)d_in[34];

  char* ws = (char*)d_ws;
  const size_t SZ_STBF = (size_t)NGNN * DDIM * sizeof(short);    // 12.6 MB
  const size_t SZ_AGG  = (size_t)NGNN * DDIM * sizeof(float);    // 25.2 MB
  const size_t SZ_REP  = (size_t)NREP * REP_STRIDE * sizeof(float); // 10.75 MB
  unsigned short* stbf = (unsigned short*)ws;
  float* agg       = (float*)(ws + SZ_STBF);
  float* nf        = agg;  // decode output overlays agg (dead before first memset)
  float* REP       = (float*)(ws + SZ_STBF + SZ_AGG);
  float* fin       = (float*)(ws + SZ_STBF + SZ_AGG + SZ_REP);
  short* pk        = (short*)(ws + SZ_STBF + SZ_AGG + SZ_REP +
                              (((size_t)REP_STRIDE * 4 + 255) / 256) * 256);
  short* pWm1  = pk;             // 6*12*512
  short* pWa1e = pWm1  + 36864;  // 6*8*512
  short* pWm2  = pWa1e + 24576;  // 6*12*512
  short* pWa2e = pWm2  + 36864;  // 4*12*512
  short* pWt1  = pWa2e + 24576;  // 6*8*512
  short* pWt2  = pWt1  + 24576;  // 4*8*512
  short* pWt3  = pWt2  + 16384;  // 4*2*512
  short* pWh1  = pWt3  + 4096;   // 6*8*512
  short* pWh2  = pWh1  + 24576;  // 4*8*512
  short* pWh3  = pWh2  + 16384;  // 4*2*512
  short* pWih  = pWh3  + 4096;   // 6*36*512
  short* pWhh  = pWih  + 110592; // 6*36*512

  // pack weights to bf16 B-fragment layout (grid = (K/32)*CT)
  k_pack<<<72, 64, 0, stream>>>(Wm1,  pWm1,  192, 12);
  k_pack<<<48, 64, 0, stream>>>(Wa1,  pWa1e, 128, 8);
  k_pack<<<72, 64, 0, stream>>>(Wm2,  pWm2,  192, 12);
  k_pack<<<48, 64, 0, stream>>>(Wa2,  pWa2e, 192, 12);
  k_pack<<<48, 64, 0, stream>>>(Wt1,  pWt1,  128, 8);
  k_pack<<<32, 64, 0, stream>>>(Wt2,  pWt2,  128, 8);
  k_pack<<< 8, 64, 0, stream>>>(Wt3,  pWt3,   20, 2);
  k_pack<<<48, 64, 0, stream>>>(Wha1, pWh1,  128, 8);
  k_pack<<<32, 64, 0, stream>>>(Wha2, pWh2,  128, 8);
  k_pack<<< 8, 64, 0, stream>>>(Wha3, pWh3,   20, 2);
  k_pack<<<216, 64, 0, stream>>>(Wih, pWih,  576, 36);
  k_pack<<<216, 64, 0, stream>>>(Whh, pWhh,  576, 36);

  k_dec<<<NGNN, 128, 0, stream>>>(A, Wdec, bdec, nf);
  k_state<<<NGNN, 192, 0, stream>>>(nf, cemb, nif, cl, stbf);
  for (int p = 0; p < 2; p++) {
    hipMemsetAsync(agg, 0, SZ_AGG, stream);
    k_edge_mfma<<<NEDGE / 32, 128, 0, stream>>>(stbf, edges, attidx,
        Wm1, bm1, pWm1, pWm2, bm2, Wa1, ba1, pWa1e, pWa2e, ba2, agg);
    k_gru_mfma<<<NGNN / 64, 256, 0, stream>>>(stbf, agg, pWih, bih, pWhh, bhh);
  }
  hipMemsetAsync(REP, 0, SZ_REP, stream);
  k_head_mfma<<<(NEOUT + 63) / 64, 512, 0, stream>>>(stbf, nig, label, subidx,
      pWt1, bt1, pWt2, bt2, pWt3, bt3, pWh1, hba1, pWh2, hba2, pWh3, hba3, REP);
  k_red<<<(REP_STRIDE + 255) / 256, 256, 0, stream>>>(REP, fin);
  k_final<<<1, 1024, 0, stream>>>(fin, (float*)d_out);
}